// Round 4
// baseline (573.661 us; speedup 1.0000x reference)
//
#include <hip/hip_runtime.h>

typedef unsigned short u16;
typedef __attribute__((ext_vector_type(8))) short short8;
typedef __attribute__((ext_vector_type(4))) float f32x4;
typedef __attribute__((ext_vector_type(4))) unsigned short u16x4;

#define SEQ 2048
#define DM 1024
#define NTOK 8192  // B*L
#define CH 64      // scan chunk length
#define NCH 32     // SEQ / CH

__device__ __forceinline__ float b2f(u16 u) {
  union { float f; unsigned int i; } x; x.i = ((unsigned int)u) << 16; return x.f;
}
__device__ __forceinline__ u16 f2b(float f) {
  union { float f; unsigned int i; } x; x.f = f;
  unsigned int i = x.i;
  unsigned int r = (i + 0x7FFFu + ((i >> 16) & 1u)) >> 16;
  return (u16)r;
}

__device__ __forceinline__ void gload16(const u16* g, u16* l) {
  __builtin_amdgcn_global_load_lds(
      (const __attribute__((address_space(1))) void*)g,
      (__attribute__((address_space(3))) void*)l, 16, 0, 0);
}

// ---------------- weight transpose f32 (K x N) -> bf16 (N x K) ----------------
__global__ __launch_bounds__(256)
void wtrans(const float* __restrict__ in, u16* __restrict__ out,
            int K, int N, int rowOff, int ldOut)
{
  __shared__ float tile[32][33];
  const int n0 = blockIdx.x * 32;
  const int k0 = blockIdx.y * 32;
  const int tx = threadIdx.x, ty = threadIdx.y;
#pragma unroll
  for (int i = 0; i < 32; i += 8) {
    int k = k0 + ty + i, n = n0 + tx;
    tile[ty + i][tx] = (k < K && n < N) ? in[(long)k * N + n] : 0.f;
  }
  __syncthreads();
#pragma unroll
  for (int i = 0; i < 32; i += 8) {
    int n = n0 + ty + i, k = k0 + tx;
    if (n < N && k < K) out[(long)(rowOff + n) * ldOut + k] = f2b(tile[tx][ty + i]);
  }
}

// Bp_w/Cp_w (1024x16) -> rows [1024..1055] of WcatT (ld 1024)
__global__ __launch_bounds__(256)
void small_trans(const float* __restrict__ Bp, const float* __restrict__ Cp,
                 u16* __restrict__ wcatT)
{
  int t = blockIdx.x * 256 + threadIdx.x;  // 16384 threads
  int n = t >> 10, k = t & 1023;
  wcatT[(long)(1024 + n) * 1024 + k] = f2b(Bp[(long)k * 16 + n]);
  wcatT[(long)(1040 + n) * 1024 + k] = f2b(Cp[(long)k * 16 + n]);
}

// ---------------- LayerNorm helpers ----------------
__device__ __forceinline__ void blockReduce2(float& a, float& b, float* s)
{
#pragma unroll
  for (int off = 32; off > 0; off >>= 1) {
    a += __shfl_xor(a, off);
    b += __shfl_xor(b, off);
  }
  const int lane = threadIdx.x & 63, wid = threadIdx.x >> 6;
  __syncthreads();
  if (lane == 0) { s[wid] = a; s[4 + wid] = b; }
  __syncthreads();
  a = s[0] + s[1] + s[2] + s[3];
  b = s[4] + s[5] + s[6] + s[7];
}

// fused LN1 -> LN2, f32 in, bf16 out (row length 1024, 256 thr x 4 elems)
__global__ __launch_bounds__(256)
void ln_ln_kernel(const float* __restrict__ x, const float* __restrict__ g1,
                  const float* __restrict__ b1, const float* __restrict__ g2,
                  const float* __restrict__ b2, u16* __restrict__ out)
{
  __shared__ float sred[8];
  const long row = blockIdx.x;
  const int t = threadIdx.x;
  const float4 xv = ((const float4*)(x + row * DM))[t];
  float s = xv.x + xv.y + xv.z + xv.w;
  float sq = xv.x * xv.x + xv.y * xv.y + xv.z * xv.z + xv.w * xv.w;
  blockReduce2(s, sq, sred);
  const float mu = s * (1.f / DM);
  const float rs = rsqrtf(sq * (1.f / DM) - mu * mu + 1e-5f);
  const float4 g1v = ((const float4*)g1)[t];
  const float4 b1v = ((const float4*)b1)[t];
  float xn[4];
  xn[0] = (xv.x - mu) * rs * g1v.x + b1v.x;
  xn[1] = (xv.y - mu) * rs * g1v.y + b1v.y;
  xn[2] = (xv.z - mu) * rs * g1v.z + b1v.z;
  xn[3] = (xv.w - mu) * rs * g1v.w + b1v.w;
  float s2 = xn[0] + xn[1] + xn[2] + xn[3];
  float sq2 = xn[0] * xn[0] + xn[1] * xn[1] + xn[2] * xn[2] + xn[3] * xn[3];
  blockReduce2(s2, sq2, sred);
  const float mu2 = s2 * (1.f / DM);
  const float rs2 = rsqrtf(sq2 * (1.f / DM) - mu2 * mu2 + 1e-5f);
  const float4 g2v = ((const float4*)g2)[t];
  const float4 b2v = ((const float4*)b2)[t];
  u16x4 o;
  o[0] = f2b((xn[0] - mu2) * rs2 * g2v.x + b2v.x);
  o[1] = f2b((xn[1] - mu2) * rs2 * g2v.y + b2v.y);
  o[2] = f2b((xn[2] - mu2) * rs2 * g2v.z + b2v.z);
  o[3] = f2b((xn[3] - mu2) * rs2 * g2v.w + b2v.w);
  *(u16x4*)(out + row * DM + t * 4) = o;
}

// single LN, f32 in, bf16 out
__global__ __launch_bounds__(256)
void ln_kernel(const float* __restrict__ x, const float* __restrict__ g,
               const float* __restrict__ b, u16* __restrict__ out)
{
  __shared__ float sred[8];
  const long row = blockIdx.x;
  const int t = threadIdx.x;
  const float4 xv = ((const float4*)(x + row * DM))[t];
  float s = xv.x + xv.y + xv.z + xv.w;
  float sq = xv.x * xv.x + xv.y * xv.y + xv.z * xv.z + xv.w * xv.w;
  blockReduce2(s, sq, sred);
  const float mu = s * (1.f / DM);
  const float rs = rsqrtf(sq * (1.f / DM) - mu * mu + 1e-5f);
  const float4 gv = ((const float4*)g)[t];
  const float4 bv = ((const float4*)b)[t];
  u16x4 o;
  o[0] = f2b((xv.x - mu) * rs * gv.x + bv.x);
  o[1] = f2b((xv.y - mu) * rs * gv.y + bv.y);
  o[2] = f2b((xv.z - mu) * rs * gv.z + bv.z);
  o[3] = f2b((xv.w - mu) * rs * gv.w + bv.w);
  *(u16x4*)(out + row * DM + t * 4) = o;
}

// ---------------- depthwise conv (k=3, pad 1 along L) + silu, vectorized ----------------
__global__ __launch_bounds__(256)
void conv_silu_kernel(const u16* __restrict__ x1, const float* __restrict__ w,
                      u16* __restrict__ xc)
{
  const long i8 = (long)blockIdx.x * 256 + threadIdx.x;  // NTOK*DM/8
  const long base = i8 * 8;
  const int d0 = (int)(base & (DM - 1));
  const long m = base >> 10;
  const int l = (int)(m & (SEQ - 1));
  const short8 cv = *(const short8*)(x1 + base);
  short8 lv = {}, rv = {};
  if (l > 0) lv = *(const short8*)(x1 + base - DM);
  if (l < SEQ - 1) rv = *(const short8*)(x1 + base + DM);
  short8 o;
#pragma unroll
  for (int j = 0; j < 8; ++j) {
    const int d = d0 + j;
    const float a = b2f((u16)lv[j]) * w[d * 3 + 0] + b2f((u16)cv[j]) * w[d * 3 + 1]
                  + b2f((u16)rv[j]) * w[d * 3 + 2];
    o[j] = (short)f2b(a / (1.f + __expf(-a)));
  }
  *(short8*)(xc + base) = o;
}

// ---------------- GEMM: C = A(MxK, bf16) * BT(NxK, bf16)^T ----------------
// 256x128 tile, 8 waves (512 thr), 4-buffer depth-3 prefetch pipeline with
// counted vmcnt (never drains to 0 in steady state), raw s_barrier,
// slot-XOR LDS swizzle (both sides), XCD-chunked bid swizzle.
// MODE 2: bf16 out = gelu_exact(acc + bias)
// MODE 3: f32  out = acc + bias + resid
// MODE 4: dtBC: ld 1152 f32; col<1024 softplus(+bias); col<1040 +bias2; col<1056 +bias3
// MODE 5: fused w1|v1 (N=2048): col<1024 -> outp (bf16, +bias); else silu -> outp2 (+bias2)
template <int MODE>
__global__ __launch_bounds__(512)
void gemm_bt(const u16* __restrict__ A, const u16* __restrict__ BT,
             const float* __restrict__ bias, const float* __restrict__ bias2,
             const float* __restrict__ bias3, const float* __restrict__ resid,
             void* __restrict__ outp, void* __restrict__ outp2,
             int K, int ldOut, int nbx)
{
  __shared__ u16 lds_a[4][8192];   // 4 bufs x 256 rows x 32 (64B rows)
  __shared__ u16 lds_b[4][4096];   // 4 bufs x 128 rows x 32
  const int t = threadIdx.x;
  const int lane = t & 63;
  const int wid = t >> 6;
  const int wr = wid >> 1, wc = wid & 1;   // 4x2 waves -> 64x64 per wave

  // XCD-chunked bijective swizzle (gridDim.x always a multiple of 8 here)
  int bid = blockIdx.x;
  const int qch = gridDim.x >> 3;
  bid = (bid & 7) * qch + (bid >> 3);
  const long brow = (long)(bid / nbx) * 256;
  const long bcol = (long)(bid % nbx) * 128;

  f32x4 acc[4][4] = {};

  // staging: thread t fills linear LDS slot; global source pre-swizzled so the
  // XOR-swizzled read below finds its k-slot. (slot' = slot ^ ((row>>1)&3))
  const int srow = t >> 2;                       // 0..127
  const int sslot = (t & 3) ^ ((t >> 3) & 3);
  const u16* aPtr = A + (brow + srow) * (long)K + sslot * 8;
  const u16* bPtr = BT + (bcol + srow) * (long)K + sslot * 8;
  const long rowStep = 128L * K;
  const int nk = K >> 5;                         // >= 32 for all our GEMMs

  // read-side swizzled k-slot
  const int rslot = (lane >> 4) ^ ((lane >> 1) & 3);
  const int koff = rslot * 8;
  const int arow = wr * 64 + (lane & 15);        // 0..255
  const int brw = wc * 64 + (lane & 15);         // 0..127

#define STAGE(kt, buf)                                              \
  {                                                                 \
    const int k0_ = (kt) << 5;                                      \
    gload16(aPtr + k0_, &lds_a[buf][t * 8]);                        \
    gload16(aPtr + rowStep + k0_, &lds_a[buf][4096 + t * 8]);       \
    gload16(bPtr + k0_, &lds_b[buf][t * 8]);                        \
  }

  STAGE(0, 0);
  STAGE(1, 1);
  STAGE(2, 2);
  asm volatile("s_waitcnt vmcnt(6)" ::: "memory");   // tile 0 resident
  __builtin_amdgcn_s_barrier();
  asm volatile("" ::: "memory");

  for (int kt = 0; kt < nk; ++kt) {
    const int buf = kt & 3;
    if (kt + 3 < nk) STAGE(kt + 3, (kt + 3) & 3);
    short8 af[4], bfr[4];
#pragma unroll
    for (int m = 0; m < 4; ++m)
      af[m] = *(const short8*)&lds_a[buf][(arow + m * 16) * 32 + koff];
#pragma unroll
    for (int n = 0; n < 4; ++n)
      bfr[n] = *(const short8*)&lds_b[buf][(brw + n * 16) * 32 + koff];
#pragma unroll
    for (int m = 0; m < 4; ++m)
#pragma unroll
      for (int n = 0; n < 4; ++n)
        acc[m][n] = __builtin_amdgcn_mfma_f32_16x16x32_bf16(af[m], bfr[n], acc[m][n], 0, 0, 0);
    if (kt + 1 < nk) {
      const int staged = (kt + 3 < nk) ? kt + 3 : nk - 1;
      const int beyond = staged - (kt + 1);      // 0,1,2 in-flight tiles beyond next
      if (beyond == 2)      asm volatile("s_waitcnt vmcnt(6)" ::: "memory");
      else if (beyond == 1) asm volatile("s_waitcnt vmcnt(3)" ::: "memory");
      else                  asm volatile("s_waitcnt vmcnt(0)" ::: "memory");
      __builtin_amdgcn_s_barrier();
      asm volatile("" ::: "memory");
    }
  }
#undef STAGE

  const int cc = lane & 15;
  const int r0 = (lane >> 4) * 4;
#pragma unroll
  for (int m = 0; m < 4; ++m) {
#pragma unroll
    for (int n = 0; n < 4; ++n) {
      const long col = bcol + wc * 64 + n * 16 + cc;
#pragma unroll
      for (int r = 0; r < 4; ++r) {
        const long row = brow + wr * 64 + m * 16 + r0 + r;
        float val = acc[m][n][r];
        if constexpr (MODE == 4) {
          if (col < 1024) {
            val += bias[col];
            val = (val > 20.f) ? val : log1pf(__expf(val));
            ((float*)outp)[row * 1152 + col] = val;
          } else if (col < 1040) {
            ((float*)outp)[row * 1152 + col] = val + bias2[col - 1024];
          } else if (col < 1056) {
            ((float*)outp)[row * 1152 + col] = val + bias3[col - 1040];
          }
        } else if constexpr (MODE == 5) {
          if (col < 1024) {
            val += bias[col];
            ((u16*)outp)[row * 1024 + col] = f2b(val);
          } else {
            val += bias2[col - 1024];
            val = val / (1.f + __expf(-val));
            ((u16*)outp2)[row * 1024 + col - 1024] = f2b(val);
          }
        } else {
          val += bias[col];
          if constexpr (MODE == 2) val = 0.5f * val * (1.f + erff(val * 0.70710678118f));
          if constexpr (MODE == 3) {
            ((float*)outp)[row * ldOut + col] = val + resid[row * ldOut + col];
          } else {
            ((u16*)outp)[row * ldOut + col] = f2b(val);
          }
        }
      }
    }
  }
}

// ---------------- chunked selective scan ----------------
__global__ __launch_bounds__(256)
void scan_pass1(const u16* __restrict__ xc, const float* __restrict__ dtbc,
                const float* __restrict__ A_log, float* __restrict__ hloc,
                float* __restrict__ sdt)
{
  const int bx = blockIdx.x;
  const int b = bx >> 9;
  const int ch = (bx >> 4) & 31;
  const int dBase = (bx & 15) * 64;
  const int t = threadIdx.x;
  const int dl = t >> 2;
  const int q = t & 3;
  const int d = dBase + dl;

  __shared__ float s_b[32][16];
  __shared__ float s_dt[32][64];
  __shared__ u16 s_x[32][64];

  float Areg[4];
#pragma unroll
  for (int j = 0; j < 4; ++j) Areg[j] = -__expf(A_log[d * 16 + q * 4 + j]);
  float h[4] = {0.f, 0.f, 0.f, 0.f};
  float sAcc = 0.f;
  const long mBase = (long)b * SEQ + ch * CH;

  for (int c0 = 0; c0 < CH; c0 += 32) {
#pragma unroll
    for (int i = 0; i < 2; ++i) {
      int idx = i * 256 + t;
      int s = idx >> 4, j = idx & 15;
      s_b[s][j] = dtbc[(mBase + c0 + s) * 1152 + 1024 + j];
    }
#pragma unroll
    for (int i = 0; i < 8; ++i) {
      int idx = i * 256 + t;
      int s = idx >> 6, j = idx & 63;
      long m = mBase + c0 + s;
      s_dt[s][j] = dtbc[m * 1152 + dBase + j];
      s_x[s][j] = xc[m * DM + dBase + j];
    }
    __syncthreads();
#pragma unroll 4
    for (int s = 0; s < 32; ++s) {
      const float dt = s_dt[s][dl];
      const float p = dt * b2f(s_x[s][dl]);
      sAcc += dt;
#pragma unroll
      for (int j = 0; j < 4; ++j)
        h[j] = __expf(dt * Areg[j]) * h[j] + p * s_b[s][q * 4 + j];
    }
    __syncthreads();
  }
  const long base = (((long)b * NCH + ch) * 1024 + d) * 16 + q * 4;
  float4 hv; hv.x = h[0]; hv.y = h[1]; hv.z = h[2]; hv.w = h[3];
  *(float4*)&hloc[base] = hv;
  if (q == 0) sdt[((long)b * NCH + ch) * 1024 + d] = sAcc;
}

__global__ __launch_bounds__(256)
void scan_pass2(const float* __restrict__ A_log, const float* __restrict__ sdt,
                const float* __restrict__ hloc, float* __restrict__ hin)
{
  const int tid = blockIdx.x * 256 + threadIdx.x;
  const int b = tid >> 14;
  const int dn = tid & 16383;
  const int d = dn >> 4;
  const float A = -__expf(A_log[dn]);
  float h = 0.f;
  for (int c = 0; c < NCH; ++c) {
    const long idx = (((long)b * NCH + c) << 14) + dn;
    hin[idx] = h;
    h = __expf(A * sdt[((long)b * NCH + c) * 1024 + d]) * h + hloc[idx];
  }
}

__global__ __launch_bounds__(256)
void scan_pass3(const u16* __restrict__ xc, const float* __restrict__ dtbc,
                const u16* __restrict__ vg, const float* __restrict__ A_log,
                const float* __restrict__ D_p, const float* __restrict__ hin,
                u16* __restrict__ yv)
{
  const int bx = blockIdx.x;
  const int b = bx >> 9;
  const int ch = (bx >> 4) & 31;
  const int dBase = (bx & 15) * 64;
  const int t = threadIdx.x;
  const int dl = t >> 2;
  const int q = t & 3;
  const int d = dBase + dl;

  __shared__ float s_bc[32][32];
  __shared__ float s_dt[32][64];
  __shared__ u16 s_x[32][64];
  __shared__ u16 s_v[32][64];
  __shared__ u16 s_y[32][64];

  float Areg[4];
#pragma unroll
  for (int j = 0; j < 4; ++j) Areg[j] = -__expf(A_log[d * 16 + q * 4 + j]);
  const float Dp = D_p[d];
  const float4 hv = *(const float4*)&hin[(((long)b * NCH + ch) * 1024 + d) * 16 + q * 4];
  float h[4] = {hv.x, hv.y, hv.z, hv.w};

  const long mBase = (long)b * SEQ + ch * CH;

  for (int c0 = 0; c0 < CH; c0 += 32) {
#pragma unroll
    for (int i = 0; i < 4; ++i) {
      int idx = i * 256 + t;
      int s = idx >> 5, j = idx & 31;
      s_bc[s][j] = dtbc[(mBase + c0 + s) * 1152 + 1024 + j];
    }
#pragma unroll
    for (int i = 0; i < 8; ++i) {
      int idx = i * 256 + t;
      int s = idx >> 6, j = idx & 63;
      long m = mBase + c0 + s;
      s_dt[s][j] = dtbc[m * 1152 + dBase + j];
      s_x[s][j] = xc[m * DM + dBase + j];
      s_v[s][j] = vg[m * DM + dBase + j];
    }
    __syncthreads();
#pragma unroll 4
    for (int s = 0; s < 32; ++s) {
      const float dt = s_dt[s][dl];
      const float xt = b2f(s_x[s][dl]);
      const float p = dt * xt;
      float y = 0.f;
#pragma unroll
      for (int j = 0; j < 4; ++j) {
        const float dA = __expf(dt * Areg[j]);
        h[j] = dA * h[j] + p * s_bc[s][q * 4 + j];
        y = fmaf(h[j], s_bc[s][16 + q * 4 + j], y);
      }
      y += __shfl_xor(y, 1);
      y += __shfl_xor(y, 2);
      if (q == 0) s_y[s][dl] = f2b((y + Dp * xt) * b2f(s_v[s][dl]));
    }
    __syncthreads();
#pragma unroll
    for (int i = 0; i < 8; ++i) {
      int idx = i * 256 + t;
      int s = idx >> 6, j = idx & 63;
      yv[(mBase + c0 + s) * DM + dBase + j] = s_y[s][j];
    }
    __syncthreads();
  }
}

extern "C" void kernel_launch(void* const* d_in, const int* in_sizes, int n_in,
                              void* d_out, int out_size, void* d_ws, size_t ws_size,
                              hipStream_t stream)
{
  (void)in_sizes; (void)n_in; (void)out_size; (void)ws_size;
  const float* x      = (const float*)d_in[0];
  const float* ln1_g  = (const float*)d_in[1];
  const float* ln1_b  = (const float*)d_in[2];
  const float* ln_g   = (const float*)d_in[3];
  const float* ln_b   = (const float*)d_in[4];
  const float* w1_w   = (const float*)d_in[5];
  const float* w1_b   = (const float*)d_in[6];
  const float* v1_w   = (const float*)d_in[7];
  const float* v1_b   = (const float*)d_in[8];
  const float* w2_w   = (const float*)d_in[9];
  const float* w2_b   = (const float*)d_in[10];
  const float* conv_w = (const float*)d_in[11];
  const float* dt_w   = (const float*)d_in[12];
  const float* dt_b   = (const float*)d_in[13];
  const float* Bp_w   = (const float*)d_in[14];
  const float* Bp_b   = (const float*)d_in[15];
  const float* Cp_w   = (const float*)d_in[16];
  const float* Cp_b   = (const float*)d_in[17];
  const float* A_log  = (const float*)d_in[18];
  const float* D_p    = (const float*)d_in[19];
  const float* ln2_g  = (const float*)d_in[20];
  const float* ln2_b  = (const float*)d_in[21];
  const float* ff1_w  = (const float*)d_in[22];
  const float* ff1_b  = (const float*)d_in[23];
  const float* ff2_w  = (const float*)d_in[24];
  const float* ff2_b  = (const float*)d_in[25];

  char* ws = (char*)d_ws;
  size_t cur = 0;
  auto alloc = [&](size_t bytes) -> void* {
    void* p = ws + cur;
    cur = (cur + bytes + 255) & ~(size_t)255;
    return p;
  };

  u16* wv1T  = (u16*)alloc((size_t)2048 * 1024 * 2);   // [w1T ; v1T]
  u16* w2T   = (u16*)alloc((size_t)1024 * 1024 * 2);
  u16* wcatT = (u16*)alloc((size_t)1152 * 1024 * 2);
  u16* ff1T  = (u16*)alloc((size_t)3072 * 1024 * 2);
  u16* ff2T  = (u16*)alloc((size_t)1024 * 3072 * 2);
  u16* xm    = (u16*)alloc((size_t)NTOK * DM * 2);
  u16* x1b   = (u16*)alloc((size_t)NTOK * DM * 2);
  u16* vb    = (u16*)alloc((size_t)NTOK * DM * 2);
  u16* xcb   = (u16*)alloc((size_t)NTOK * DM * 2);
  float* dtbc = (float*)alloc((size_t)NTOK * 1152 * 4);
  float* x2  = (float*)alloc((size_t)NTOK * DM * 4);
  float* hloc = (float*)alloc((size_t)4 * NCH * 1024 * 16 * 4);  // 8 MB
  float* hin  = (float*)alloc((size_t)4 * NCH * 1024 * 16 * 4);  // 8 MB
  float* sdtb = (float*)alloc((size_t)4 * NCH * 1024 * 4);       // 512 KB
  u16* yvb  = xm;        // reuse: xm dead after fused GEMM
  u16* xn2  = x1b;       // reuse: x1 dead after conv
  u16* hb   = xcb;       // reuse: xc+dtbc dead after scan

  const dim3 tb32(32, 8);
  // weight prep
  wtrans<<<dim3(32, 32), tb32, 0, stream>>>(w1_w, wv1T, 1024, 1024, 0, 1024);
  wtrans<<<dim3(32, 32), tb32, 0, stream>>>(v1_w, wv1T, 1024, 1024, 1024, 1024);
  wtrans<<<dim3(32, 32), tb32, 0, stream>>>(w2_w, w2T, 1024, 1024, 0, 1024);
  wtrans<<<dim3(32, 32), tb32, 0, stream>>>(dt_w, wcatT, 1024, 1024, 0, 1024);
  small_trans<<<64, 256, 0, stream>>>(Bp_w, Cp_w, wcatT);
  hipMemsetAsync(wcatT + (size_t)1056 * 1024, 0, (size_t)96 * 1024 * 2, stream);
  wtrans<<<dim3(96, 32), tb32, 0, stream>>>(ff1_w, ff1T, 1024, 3072, 0, 1024);
  wtrans<<<dim3(32, 96), tb32, 0, stream>>>(ff2_w, ff2T, 3072, 1024, 0, 3072);

  // LN1 -> LN2 -> xm (bf16)
  ln_ln_kernel<<<NTOK, 256, 0, stream>>>(x, ln1_g, ln1_b, ln_g, ln_b, xm);

  // fused: x1 = xm @ w1 + b ; v = silu(xm @ v1 + b)   (N=2048)
  gemm_bt<5><<<512, 512, 0, stream>>>(xm, wv1T, w1_b, v1_b, nullptr, nullptr,
                                      x1b, vb, 1024, 1024, 16);

  // xc = silu(depthwise_conv(x1))
  conv_silu_kernel<<<(NTOK * DM) / (256 * 8), 256, 0, stream>>>(x1b, conv_w, xcb);

  // dtBC = [softplus(xc@dt_w+dt_b) | xc@Bp_w+Bp_b | xc@Cp_w+Cp_b | pad]  (f32, ld 1152)
  gemm_bt<4><<<288, 512, 0, stream>>>(xcb, wcatT, dt_b, Bp_b, Cp_b, nullptr,
                                      dtbc, nullptr, 1024, 1152, 9);

  // chunked selective scan fused with y*v -> yv (bf16)
  scan_pass1<<<2048, 256, 0, stream>>>(xcb, dtbc, A_log, hloc, sdtb);
  scan_pass2<<<256, 256, 0, stream>>>(A_log, sdtb, hloc, hin);
  scan_pass3<<<2048, 256, 0, stream>>>(xcb, dtbc, vb, A_log, D_p, hin, yvb);

  // x2 = yv @ w2 + b + x (f32)
  gemm_bt<3><<<256, 512, 0, stream>>>(yvb, w2T, w2_b, nullptr, nullptr, x,
                                      x2, nullptr, 1024, 1024, 8);

  // xn2 = LN(x2) (bf16)
  ln_kernel<<<NTOK, 256, 0, stream>>>(x2, ln2_g, ln2_b, xn2);

  // h = gelu(xn2 @ ff1 + b) (bf16, ld 3072)
  gemm_bt<2><<<768, 512, 0, stream>>>(xn2, ff1T, ff1_b, nullptr, nullptr, nullptr,
                                      hb, nullptr, 1024, 3072, 24);

  // out = h @ ff2 + b + x2 (f32)
  gemm_bt<3><<<256, 512, 0, stream>>>(hb, ff2T, ff2_b, nullptr, nullptr, x2,
                                      d_out, nullptr, 3072, 1024, 8);
}

// Round 5
// 475.403 us; speedup vs baseline: 1.2067x; 1.2067x over previous
//
#include <hip/hip_runtime.h>

typedef unsigned short u16;
typedef __attribute__((ext_vector_type(8))) short short8;
typedef __attribute__((ext_vector_type(4))) float f32x4;
typedef __attribute__((ext_vector_type(4))) unsigned short u16x4;

#define SEQ 2048
#define DM 1024
#define NTOK 8192  // B*L
#define CH 64      // scan chunk length
#define NCH 32     // SEQ / CH

__device__ __forceinline__ float b2f(u16 u) {
  union { float f; unsigned int i; } x; x.i = ((unsigned int)u) << 16; return x.f;
}
__device__ __forceinline__ u16 f2b(float f) {
  union { float f; unsigned int i; } x; x.f = f;
  unsigned int i = x.i;
  unsigned int r = (i + 0x7FFFu + ((i >> 16) & 1u)) >> 16;
  return (u16)r;
}

__device__ __forceinline__ void gload16(const u16* g, u16* l) {
  __builtin_amdgcn_global_load_lds(
      (const __attribute__((address_space(1))) void*)g,
      (__attribute__((address_space(3))) void*)l, 16, 0, 0);
}

// ---------------- weight transpose f32 (K x N) -> bf16 (N x K) ----------------
__global__ __launch_bounds__(256)
void wtrans(const float* __restrict__ in, u16* __restrict__ out,
            int K, int N, int rowOff, int ldOut)
{
  __shared__ float tile[32][33];
  const int n0 = blockIdx.x * 32;
  const int k0 = blockIdx.y * 32;
  const int tx = threadIdx.x, ty = threadIdx.y;
#pragma unroll
  for (int i = 0; i < 32; i += 8) {
    int k = k0 + ty + i, n = n0 + tx;
    tile[ty + i][tx] = (k < K && n < N) ? in[(long)k * N + n] : 0.f;
  }
  __syncthreads();
#pragma unroll
  for (int i = 0; i < 32; i += 8) {
    int n = n0 + ty + i, k = k0 + tx;
    if (n < N && k < K) out[(long)(rowOff + n) * ldOut + k] = f2b(tile[tx][ty + i]);
  }
}

// Bp_w/Cp_w (1024x16) -> rows [1024..1055] of WcatT (ld 1024)
__global__ __launch_bounds__(256)
void small_trans(const float* __restrict__ Bp, const float* __restrict__ Cp,
                 u16* __restrict__ wcatT)
{
  int t = blockIdx.x * 256 + threadIdx.x;  // 16384 threads
  int n = t >> 10, k = t & 1023;
  wcatT[(long)(1024 + n) * 1024 + k] = f2b(Bp[(long)k * 16 + n]);
  wcatT[(long)(1040 + n) * 1024 + k] = f2b(Cp[(long)k * 16 + n]);
}

// ---------------- LayerNorm helpers ----------------
__device__ __forceinline__ void blockReduce2(float& a, float& b, float* s)
{
#pragma unroll
  for (int off = 32; off > 0; off >>= 1) {
    a += __shfl_xor(a, off);
    b += __shfl_xor(b, off);
  }
  const int lane = threadIdx.x & 63, wid = threadIdx.x >> 6;
  __syncthreads();
  if (lane == 0) { s[wid] = a; s[4 + wid] = b; }
  __syncthreads();
  a = s[0] + s[1] + s[2] + s[3];
  b = s[4] + s[5] + s[6] + s[7];
}

// fused LN1 -> LN2, f32 in, bf16 out (row length 1024, 256 thr x 4 elems)
__global__ __launch_bounds__(256)
void ln_ln_kernel(const float* __restrict__ x, const float* __restrict__ g1,
                  const float* __restrict__ b1, const float* __restrict__ g2,
                  const float* __restrict__ b2, u16* __restrict__ out)
{
  __shared__ float sred[8];
  const long row = blockIdx.x;
  const int t = threadIdx.x;
  const float4 xv = ((const float4*)(x + row * DM))[t];
  float s = xv.x + xv.y + xv.z + xv.w;
  float sq = xv.x * xv.x + xv.y * xv.y + xv.z * xv.z + xv.w * xv.w;
  blockReduce2(s, sq, sred);
  const float mu = s * (1.f / DM);
  const float rs = rsqrtf(sq * (1.f / DM) - mu * mu + 1e-5f);
  const float4 g1v = ((const float4*)g1)[t];
  const float4 b1v = ((const float4*)b1)[t];
  float xn[4];
  xn[0] = (xv.x - mu) * rs * g1v.x + b1v.x;
  xn[1] = (xv.y - mu) * rs * g1v.y + b1v.y;
  xn[2] = (xv.z - mu) * rs * g1v.z + b1v.z;
  xn[3] = (xv.w - mu) * rs * g1v.w + b1v.w;
  float s2 = xn[0] + xn[1] + xn[2] + xn[3];
  float sq2 = xn[0] * xn[0] + xn[1] * xn[1] + xn[2] * xn[2] + xn[3] * xn[3];
  blockReduce2(s2, sq2, sred);
  const float mu2 = s2 * (1.f / DM);
  const float rs2 = rsqrtf(sq2 * (1.f / DM) - mu2 * mu2 + 1e-5f);
  const float4 g2v = ((const float4*)g2)[t];
  const float4 b2v = ((const float4*)b2)[t];
  u16x4 o;
  o[0] = f2b((xn[0] - mu2) * rs2 * g2v.x + b2v.x);
  o[1] = f2b((xn[1] - mu2) * rs2 * g2v.y + b2v.y);
  o[2] = f2b((xn[2] - mu2) * rs2 * g2v.z + b2v.z);
  o[3] = f2b((xn[3] - mu2) * rs2 * g2v.w + b2v.w);
  *(u16x4*)(out + row * DM + t * 4) = o;
}

// single LN, f32 in, bf16 out
__global__ __launch_bounds__(256)
void ln_kernel(const float* __restrict__ x, const float* __restrict__ g,
               const float* __restrict__ b, u16* __restrict__ out)
{
  __shared__ float sred[8];
  const long row = blockIdx.x;
  const int t = threadIdx.x;
  const float4 xv = ((const float4*)(x + row * DM))[t];
  float s = xv.x + xv.y + xv.z + xv.w;
  float sq = xv.x * xv.x + xv.y * xv.y + xv.z * xv.z + xv.w * xv.w;
  blockReduce2(s, sq, sred);
  const float mu = s * (1.f / DM);
  const float rs = rsqrtf(sq * (1.f / DM) - mu * mu + 1e-5f);
  const float4 gv = ((const float4*)g)[t];
  const float4 bv = ((const float4*)b)[t];
  u16x4 o;
  o[0] = f2b((xv.x - mu) * rs * gv.x + bv.x);
  o[1] = f2b((xv.y - mu) * rs * gv.y + bv.y);
  o[2] = f2b((xv.z - mu) * rs * gv.z + bv.z);
  o[3] = f2b((xv.w - mu) * rs * gv.w + bv.w);
  *(u16x4*)(out + row * DM + t * 4) = o;
}

// ---------------- depthwise conv (k=3, pad 1 along L) + silu, vectorized ----------------
__global__ __launch_bounds__(256)
void conv_silu_kernel(const u16* __restrict__ x1, const float* __restrict__ w,
                      u16* __restrict__ xc)
{
  const long i8 = (long)blockIdx.x * 256 + threadIdx.x;  // NTOK*DM/8
  const long base = i8 * 8;
  const int d0 = (int)(base & (DM - 1));
  const long m = base >> 10;
  const int l = (int)(m & (SEQ - 1));
  const short8 cv = *(const short8*)(x1 + base);
  short8 lv = {}, rv = {};
  if (l > 0) lv = *(const short8*)(x1 + base - DM);
  if (l < SEQ - 1) rv = *(const short8*)(x1 + base + DM);
  short8 o;
#pragma unroll
  for (int j = 0; j < 8; ++j) {
    const int d = d0 + j;
    const float a = b2f((u16)lv[j]) * w[d * 3 + 0] + b2f((u16)cv[j]) * w[d * 3 + 1]
                  + b2f((u16)rv[j]) * w[d * 3 + 2];
    o[j] = (short)f2b(a / (1.f + __expf(-a)));
  }
  *(short8*)(xc + base) = o;
}

// ---------------- GEMM v1 (R3-proven): 128x128, 2-buf, 2-barrier ----------------
// MODE 3: f32  out = acc + bias + resid
// MODE 4: dtBC: ld 1152 f32; col<1024 softplus(+bias); col<1040 +bias2; col<1056 +bias3
template <int MODE>
__global__ __launch_bounds__(256)
void gemm_bt(const u16* __restrict__ A, const u16* __restrict__ BT,
             const float* __restrict__ bias, const float* __restrict__ bias2,
             const float* __restrict__ bias3, const float* __restrict__ resid,
             void* __restrict__ outp, void* __restrict__ outp2,
             int K, int ldOut, int nbx)
{
  __shared__ u16 lds_a[2][4096];
  __shared__ u16 lds_b[2][4096];
  const int t = threadIdx.x;
  const int lane = t & 63;
  const int wid = t >> 6;
  const int wr = wid >> 1, wc = wid & 1;

  int bid = blockIdx.x;
  const int qch = gridDim.x >> 3;
  bid = (bid & 7) * qch + (bid >> 3);
  const long brow = (long)(bid / nbx) * 128;
  const long bcol = (long)(bid % nbx) * 128;

  f32x4 acc[4][4] = {};

  const int srow = t >> 2;
  const int sslot = (t & 3) ^ ((t >> 3) & 3);
  const u16* aPtr = A + (brow + srow) * (long)K + sslot * 8;
  const u16* bPtr = BT + (bcol + srow) * (long)K + sslot * 8;
  u16* la = &lds_a[0][t * 8];
  u16* lb = &lds_b[0][t * 8];
  const long rowStep = 64L * K;
  const int nk = K >> 5;

  const int rslot = (lane >> 4) ^ ((lane >> 1) & 3);
  const int koff = rslot * 8;
  const int arow = wr * 64 + (lane & 15);
  const int brw = wc * 64 + (lane & 15);

#define STAGE(kt, buf)                                              \
  {                                                                 \
    const int k0_ = (kt) << 5;                                      \
    gload16(aPtr + k0_, la + (buf) * 4096);                         \
    gload16(aPtr + rowStep + k0_, la + (buf) * 4096 + 2048);        \
    gload16(bPtr + k0_, lb + (buf) * 4096);                         \
    gload16(bPtr + rowStep + k0_, lb + (buf) * 4096 + 2048);        \
  }

  STAGE(0, 0);
  __syncthreads();
  int cur = 0;
  for (int kt = 0; kt < nk; ++kt) {
    if (kt + 1 < nk) STAGE(kt + 1, cur ^ 1);
    short8 af[4], bfr[4];
#pragma unroll
    for (int m = 0; m < 4; ++m)
      af[m] = *(const short8*)&lds_a[cur][(arow + m * 16) * 32 + koff];
#pragma unroll
    for (int n = 0; n < 4; ++n)
      bfr[n] = *(const short8*)&lds_b[cur][(brw + n * 16) * 32 + koff];
#pragma unroll
    for (int m = 0; m < 4; ++m)
#pragma unroll
      for (int n = 0; n < 4; ++n)
        acc[m][n] = __builtin_amdgcn_mfma_f32_16x16x32_bf16(af[m], bfr[n], acc[m][n], 0, 0, 0);
    __syncthreads();
    cur ^= 1;
  }
#undef STAGE

  const int cc = lane & 15;
  const int r0 = (lane >> 4) * 4;
#pragma unroll
  for (int m = 0; m < 4; ++m) {
#pragma unroll
    for (int n = 0; n < 4; ++n) {
      const long col = bcol + wc * 64 + n * 16 + cc;
#pragma unroll
      for (int r = 0; r < 4; ++r) {
        const long row = brow + wr * 64 + m * 16 + r0 + r;
        float val = acc[m][n][r];
        if constexpr (MODE == 4) {
          if (col < 1024) {
            val += bias[col];
            val = (val > 20.f) ? val : log1pf(__expf(val));
            ((float*)outp)[row * 1152 + col] = val;
          } else if (col < 1040) {
            ((float*)outp)[row * 1152 + col] = val + bias2[col - 1024];
          } else if (col < 1056) {
            ((float*)outp)[row * 1152 + col] = val + bias3[col - 1040];
          }
        } else {
          val += bias[col];
          if constexpr (MODE == 3) {
            ((float*)outp)[row * ldOut + col] = val + resid[row * ldOut + col];
          } else {
            ((u16*)outp)[row * ldOut + col] = f2b(val);
          }
        }
      }
    }
  }
}

// ---------------- GEMM v2: 256x256, BK=64, 8 waves, 4-phase interleaved pipeline ----
// Half-slots: LA/LB[parity][half][128x64 bf16, 16KB]. Per K-tile 4 phases:
//   P1: A-lo x B-lo   (12 ds_read)  stage A-hi[kt+1]
//   P2: A-lo x B-hi   ( 4 ds_read)  stage B-lo[kt+1]
//   P3: A-hi x B-hi   ( 8 ds_read)  stage A-lo[kt+2]
//   P4: A-hi x B-lo   ( 0 ds_read)  stage B-hi[kt+2]
// One counted vmcnt(4) per K-tile (end of P4); never drains in steady state.
// XOR 16B-slot swizzle (slot ^ (row&7)), pre-swizzled global source (rule #21).
// MODE 2: bf16 out = gelu_exact(acc + bias)
// MODE 5: fused w1|v1 (N=2048): col<1024 -> outp (bf16, +bias); else silu -> outp2 (+bias2)
template <int MODE>
__global__ __launch_bounds__(512, 2)
void gemm8p(const u16* __restrict__ A, const u16* __restrict__ BT,
            const float* __restrict__ bias, const float* __restrict__ bias2,
            void* __restrict__ outp, void* __restrict__ outp2,
            int K, int ldOut, int nbx)
{
  __shared__ u16 LA[2][2][8192];   // 64 KB
  __shared__ u16 LB[2][2][8192];   // 64 KB
  const int t = threadIdx.x;
  const int lane = t & 63;
  const int wid = t >> 6;
  const int wr = wid >> 2;         // 0..1 : 64-row stripe within each 128-half
  const int wc = wid & 3;          // 0..3 : 32-col stripe within each 128-half

  int bid = blockIdx.x;
  const int qch = gridDim.x >> 3;
  bid = (bid & 7) * qch + (bid >> 3);
  const long brow = (long)(bid / nbx) * 256;
  const long bcol = (long)(bid % nbx) * 256;

  f32x4 acc[8][4] = {};

  // staging addressing: thread t fills 16B LDS slot (row = t>>3 (+64*i), slot = t&7);
  // global source slot pre-swizzled: sc = (t&7) ^ (row&7)
  const int srow = t >> 3;                  // 0..63
  const int sc = (t & 7) ^ (srow & 7);
  const u16* aBase = A + (brow + srow) * (long)K + sc * 8;
  const u16* bBase = BT + (bcol + srow) * (long)K + sc * 8;
  const long halfStep = 128L * (long)K;
  const long rowStep = 64L * (long)K;
  const int nt = K >> 6;                    // BK=64 tiles (K >= 128 required)

  // ds_read byte offsets within a 16KB half (row*128 + (slot ^ (row&7))*16),
  // slot = kh*4 + (lane>>4); row&7 == lane&7 for all our frag rows.
  const int l15 = lane & 15, l4 = lane >> 4, l7 = lane & 7;
  const int aoff0 = (wr * 64 + l15) * 128 + ((l4 ^ l7) * 16);
  const int aoff1 = (wr * 64 + l15) * 128 + (((4 | l4) ^ l7) * 16);
  const int boff0 = (wc * 32 + l15) * 128 + ((l4 ^ l7) * 16);
  const int boff1 = (wc * 32 + l15) * 128 + (((4 | l4) ^ l7) * 16);

#define SGA(kt_, h_) { const int p_ = (kt_) & 1;                                    \
    gload16(aBase + (h_) * halfStep + (long)(kt_) * 64, &LA[p_][h_][t * 8]);        \
    gload16(aBase + (h_) * halfStep + rowStep + (long)(kt_) * 64,                   \
            &LA[p_][h_][4096 + t * 8]); }
#define SGB(kt_, h_) { const int p_ = (kt_) & 1;                                    \
    gload16(bBase + (h_) * halfStep + (long)(kt_) * 64, &LB[p_][h_][t * 8]);        \
    gload16(bBase + (h_) * halfStep + rowStep + (long)(kt_) * 64,                   \
            &LB[p_][h_][4096 + t * 8]); }

  // prologue (stream order matters for the counted waits):
  // A-lo[0], B-hi[0], A-hi[0], B-lo[0], A-lo[1], B-hi[1]
  SGA(0, 0); SGB(0, 1); SGA(0, 1); SGB(0, 0); SGA(1, 0); SGB(1, 1);
  asm volatile("s_waitcnt vmcnt(4)" ::: "memory");   // B-lo[0] resident; 2 halves in flight
  __builtin_amdgcn_s_barrier();

  short8 af[8], bl[4], bh[4];
  for (int kt = 0; kt < nt; ++kt) {
    const int par = kt & 1;
    const char* bAlo = (const char*)&LA[par][0][0];
    const char* bAhi = (const char*)&LA[par][1][0];
    const char* bBlo = (const char*)&LB[par][0][0];
    const char* bBhi = (const char*)&LB[par][1][0];

    // ---------- phase 1: A-lo x B-lo ----------
#pragma unroll
    for (int m2 = 0; m2 < 4; ++m2) {
      af[m2 * 2 + 0] = *(const short8*)(bAlo + aoff0 + m2 * 2048);
      af[m2 * 2 + 1] = *(const short8*)(bAlo + aoff1 + m2 * 2048);
    }
#pragma unroll
    for (int n2 = 0; n2 < 2; ++n2) {
      bl[n2 * 2 + 0] = *(const short8*)(bBlo + boff0 + n2 * 2048);
      bl[n2 * 2 + 1] = *(const short8*)(bBlo + boff1 + n2 * 2048);
    }
    if (kt + 1 < nt) SGA(kt + 1, 1);
    __builtin_amdgcn_s_barrier();
    __builtin_amdgcn_s_setprio(1);
#pragma unroll
    for (int m2 = 0; m2 < 4; ++m2)
#pragma unroll
      for (int n2 = 0; n2 < 2; ++n2) {
        acc[m2][n2] = __builtin_amdgcn_mfma_f32_16x16x32_bf16(af[m2*2+0], bl[n2*2+0], acc[m2][n2], 0, 0, 0);
        acc[m2][n2] = __builtin_amdgcn_mfma_f32_16x16x32_bf16(af[m2*2+1], bl[n2*2+1], acc[m2][n2], 0, 0, 0);
      }
    __builtin_amdgcn_s_setprio(0);
    __builtin_amdgcn_s_barrier();

    // ---------- phase 2: A-lo x B-hi ----------
#pragma unroll
    for (int n2 = 0; n2 < 2; ++n2) {
      bh[n2 * 2 + 0] = *(const short8*)(bBhi + boff0 + n2 * 2048);
      bh[n2 * 2 + 1] = *(const short8*)(bBhi + boff1 + n2 * 2048);
    }
    if (kt + 1 < nt) SGB(kt + 1, 0);
    __builtin_amdgcn_s_barrier();
    __builtin_amdgcn_s_setprio(1);
#pragma unroll
    for (int m2 = 0; m2 < 4; ++m2)
#pragma unroll
      for (int n2 = 0; n2 < 2; ++n2) {
        acc[m2][2 + n2] = __builtin_amdgcn_mfma_f32_16x16x32_bf16(af[m2*2+0], bh[n2*2+0], acc[m2][2 + n2], 0, 0, 0);
        acc[m2][2 + n2] = __builtin_amdgcn_mfma_f32_16x16x32_bf16(af[m2*2+1], bh[n2*2+1], acc[m2][2 + n2], 0, 0, 0);
      }
    __builtin_amdgcn_s_setprio(0);
    __builtin_amdgcn_s_barrier();

    // ---------- phase 3: A-hi x B-hi ----------
#pragma unroll
    for (int m2 = 0; m2 < 4; ++m2) {
      af[m2 * 2 + 0] = *(const short8*)(bAhi + aoff0 + m2 * 2048);
      af[m2 * 2 + 1] = *(const short8*)(bAhi + aoff1 + m2 * 2048);
    }
    if (kt + 2 < nt) SGA(kt + 2, 0);
    __builtin_amdgcn_s_barrier();
    __builtin_amdgcn_s_setprio(1);
#pragma unroll
    for (int m2 = 0; m2 < 4; ++m2)
#pragma unroll
      for (int n2 = 0; n2 < 2; ++n2) {
        acc[4 + m2][2 + n2] = __builtin_amdgcn_mfma_f32_16x16x32_bf16(af[m2*2+0], bh[n2*2+0], acc[4 + m2][2 + n2], 0, 0, 0);
        acc[4 + m2][2 + n2] = __builtin_amdgcn_mfma_f32_16x16x32_bf16(af[m2*2+1], bh[n2*2+1], acc[4 + m2][2 + n2], 0, 0, 0);
      }
    __builtin_amdgcn_s_setprio(0);
    __builtin_amdgcn_s_barrier();

    // ---------- phase 4: A-hi x B-lo (all regs resident) ----------
    if (kt + 2 < nt) SGB(kt + 2, 1);
    __builtin_amdgcn_s_setprio(1);
#pragma unroll
    for (int m2 = 0; m2 < 4; ++m2)
#pragma unroll
      for (int n2 = 0; n2 < 2; ++n2) {
        acc[4 + m2][n2] = __builtin_amdgcn_mfma_f32_16x16x32_bf16(af[m2*2+0], bl[n2*2+0], acc[4 + m2][n2], 0, 0, 0);
        acc[4 + m2][n2] = __builtin_amdgcn_mfma_f32_16x16x32_bf16(af[m2*2+1], bl[n2*2+1], acc[4 + m2][n2], 0, 0, 0);
      }
    __builtin_amdgcn_s_setprio(0);
    if (kt + 2 < nt)      asm volatile("s_waitcnt vmcnt(4)" ::: "memory");
    else if (kt + 1 < nt) asm volatile("s_waitcnt vmcnt(0)" ::: "memory");
    if (kt + 1 < nt) __builtin_amdgcn_s_barrier();
  }
#undef SGA
#undef SGB

  const int cc = lane & 15;
  const int r0 = (lane >> 4) * 4;
#pragma unroll
  for (int m = 0; m < 8; ++m) {
    const long row0 = brow + (m >> 2) * 128 + wr * 64 + (m & 3) * 16 + r0;
#pragma unroll
    for (int n = 0; n < 4; ++n) {
      const long col = bcol + (n >> 1) * 128 + wc * 32 + (n & 1) * 16 + cc;
#pragma unroll
      for (int r = 0; r < 4; ++r) {
        const long row = row0 + r;
        float val = acc[m][n][r];
        if constexpr (MODE == 5) {
          if (col < 1024) {
            val += bias[col];
            ((u16*)outp)[row * 1024 + col] = f2b(val);
          } else {
            val += bias2[col - 1024];
            val = val / (1.f + __expf(-val));
            ((u16*)outp2)[row * 1024 + col - 1024] = f2b(val);
          }
        } else {  // MODE 2: gelu
          val += bias[col];
          val = 0.5f * val * (1.f + erff(val * 0.70710678118f));
          ((u16*)outp)[row * ldOut + col] = f2b(val);
        }
      }
    }
  }
}

// ---------------- chunked selective scan ----------------
__global__ __launch_bounds__(256)
void scan_pass1(const u16* __restrict__ xc, const float* __restrict__ dtbc,
                const float* __restrict__ A_log, float* __restrict__ hloc,
                float* __restrict__ sdt)
{
  const int bx = blockIdx.x;
  const int b = bx >> 9;
  const int ch = (bx >> 4) & 31;
  const int dBase = (bx & 15) * 64;
  const int t = threadIdx.x;
  const int dl = t >> 2;
  const int q = t & 3;
  const int d = dBase + dl;

  __shared__ float s_b[32][16];
  __shared__ float s_dt[32][64];
  __shared__ u16 s_x[32][64];

  float Areg[4];
#pragma unroll
  for (int j = 0; j < 4; ++j) Areg[j] = -__expf(A_log[d * 16 + q * 4 + j]);
  float h[4] = {0.f, 0.f, 0.f, 0.f};
  float sAcc = 0.f;
  const long mBase = (long)b * SEQ + ch * CH;

  for (int c0 = 0; c0 < CH; c0 += 32) {
#pragma unroll
    for (int i = 0; i < 2; ++i) {
      int idx = i * 256 + t;
      int s = idx >> 4, j = idx & 15;
      s_b[s][j] = dtbc[(mBase + c0 + s) * 1152 + 1024 + j];
    }
#pragma unroll
    for (int i = 0; i < 8; ++i) {
      int idx = i * 256 + t;
      int s = idx >> 6, j = idx & 63;
      long m = mBase + c0 + s;
      s_dt[s][j] = dtbc[m * 1152 + dBase + j];
      s_x[s][j] = xc[m * DM + dBase + j];
    }
    __syncthreads();
#pragma unroll 4
    for (int s = 0; s < 32; ++s) {
      const float dt = s_dt[s][dl];
      const float p = dt * b2f(s_x[s][dl]);
      sAcc += dt;
#pragma unroll
      for (int j = 0; j < 4; ++j)
        h[j] = __expf(dt * Areg[j]) * h[j] + p * s_b[s][q * 4 + j];
    }
    __syncthreads();
  }
  const long base = (((long)b * NCH + ch) * 1024 + d) * 16 + q * 4;
  float4 hv; hv.x = h[0]; hv.y = h[1]; hv.z = h[2]; hv.w = h[3];
  *(float4*)&hloc[base] = hv;
  if (q == 0) sdt[((long)b * NCH + ch) * 1024 + d] = sAcc;
}

__global__ __launch_bounds__(256)
void scan_pass2(const float* __restrict__ A_log, const float* __restrict__ sdt,
                const float* __restrict__ hloc, float* __restrict__ hin)
{
  const int tid = blockIdx.x * 256 + threadIdx.x;
  const int b = tid >> 14;
  const int dn = tid & 16383;
  const int d = dn >> 4;
  const float A = -__expf(A_log[dn]);
  float h = 0.f;
  for (int c = 0; c < NCH; ++c) {
    const long idx = (((long)b * NCH + c) << 14) + dn;
    hin[idx] = h;
    h = __expf(A * sdt[((long)b * NCH + c) * 1024 + d]) * h + hloc[idx];
  }
}

__global__ __launch_bounds__(256)
void scan_pass3(const u16* __restrict__ xc, const float* __restrict__ dtbc,
                const u16* __restrict__ vg, const float* __restrict__ A_log,
                const float* __restrict__ D_p, const float* __restrict__ hin,
                u16* __restrict__ yv)
{
  const int bx = blockIdx.x;
  const int b = bx >> 9;
  const int ch = (bx >> 4) & 31;
  const int dBase = (bx & 15) * 64;
  const int t = threadIdx.x;
  const int dl = t >> 2;
  const int q = t & 3;
  const int d = dBase + dl;

  __shared__ float s_bc[32][32];
  __shared__ float s_dt[32][64];
  __shared__ u16 s_x[32][64];
  __shared__ u16 s_v[32][64];
  __shared__ u16 s_y[32][64];

  float Areg[4];
#pragma unroll
  for (int j = 0; j < 4; ++j) Areg[j] = -__expf(A_log[d * 16 + q * 4 + j]);
  const float Dp = D_p[d];
  const float4 hv = *(const float4*)&hin[(((long)b * NCH + ch) * 1024 + d) * 16 + q * 4];
  float h[4] = {hv.x, hv.y, hv.z, hv.w};

  const long mBase = (long)b * SEQ + ch * CH;

  for (int c0 = 0; c0 < CH; c0 += 32) {
#pragma unroll
    for (int i = 0; i < 4; ++i) {
      int idx = i * 256 + t;
      int s = idx >> 5, j = idx & 31;
      s_bc[s][j] = dtbc[(mBase + c0 + s) * 1152 + 1024 + j];
    }
#pragma unroll
    for (int i = 0; i < 8; ++i) {
      int idx = i * 256 + t;
      int s = idx >> 6, j = idx & 63;
      long m = mBase + c0 + s;
      s_dt[s][j] = dtbc[m * 1152 + dBase + j];
      s_x[s][j] = xc[m * DM + dBase + j];
      s_v[s][j] = vg[m * DM + dBase + j];
    }
    __syncthreads();
#pragma unroll 4
    for (int s = 0; s < 32; ++s) {
      const float dt = s_dt[s][dl];
      const float xt = b2f(s_x[s][dl]);
      const float p = dt * xt;
      float y = 0.f;
#pragma unroll
      for (int j = 0; j < 4; ++j) {
        const float dA = __expf(dt * Areg[j]);
        h[j] = dA * h[j] + p * s_bc[s][q * 4 + j];
        y = fmaf(h[j], s_bc[s][16 + q * 4 + j], y);
      }
      y += __shfl_xor(y, 1);
      y += __shfl_xor(y, 2);
      if (q == 0) s_y[s][dl] = f2b((y + Dp * xt) * b2f(s_v[s][dl]));
    }
    __syncthreads();
#pragma unroll
    for (int i = 0; i < 8; ++i) {
      int idx = i * 256 + t;
      int s = idx >> 6, j = idx & 63;
      yv[(mBase + c0 + s) * DM + dBase + j] = s_y[s][j];
    }
    __syncthreads();
  }
}

extern "C" void kernel_launch(void* const* d_in, const int* in_sizes, int n_in,
                              void* d_out, int out_size, void* d_ws, size_t ws_size,
                              hipStream_t stream)
{
  (void)in_sizes; (void)n_in; (void)out_size; (void)ws_size;
  const float* x      = (const float*)d_in[0];
  const float* ln1_g  = (const float*)d_in[1];
  const float* ln1_b  = (const float*)d_in[2];
  const float* ln_g   = (const float*)d_in[3];
  const float* ln_b   = (const float*)d_in[4];
  const float* w1_w   = (const float*)d_in[5];
  const float* w1_b   = (const float*)d_in[6];
  const float* v1_w   = (const float*)d_in[7];
  const float* v1_b   = (const float*)d_in[8];
  const float* w2_w   = (const float*)d_in[9];
  const float* w2_b   = (const float*)d_in[10];
  const float* conv_w = (const float*)d_in[11];
  const float* dt_w   = (const float*)d_in[12];
  const float* dt_b   = (const float*)d_in[13];
  const float* Bp_w   = (const float*)d_in[14];
  const float* Bp_b   = (const float*)d_in[15];
  const float* Cp_w   = (const float*)d_in[16];
  const float* Cp_b   = (const float*)d_in[17];
  const float* A_log  = (const float*)d_in[18];
  const float* D_p    = (const float*)d_in[19];
  const float* ln2_g  = (const float*)d_in[20];
  const float* ln2_b  = (const float*)d_in[21];
  const float* ff1_w  = (const float*)d_in[22];
  const float* ff1_b  = (const float*)d_in[23];
  const float* ff2_w  = (const float*)d_in[24];
  const float* ff2_b  = (const float*)d_in[25];

  char* ws = (char*)d_ws;
  size_t cur = 0;
  auto alloc = [&](size_t bytes) -> void* {
    void* p = ws + cur;
    cur = (cur + bytes + 255) & ~(size_t)255;
    return p;
  };

  u16* wv1T  = (u16*)alloc((size_t)2048 * 1024 * 2);   // [w1T ; v1T]
  u16* w2T   = (u16*)alloc((size_t)1024 * 1024 * 2);
  u16* wcatT = (u16*)alloc((size_t)1152 * 1024 * 2);
  u16* ff1T  = (u16*)alloc((size_t)3072 * 1024 * 2);
  u16* ff2T  = (u16*)alloc((size_t)1024 * 3072 * 2);
  u16* xm    = (u16*)alloc((size_t)NTOK * DM * 2);
  u16* x1b   = (u16*)alloc((size_t)NTOK * DM * 2);
  u16* vb    = (u16*)alloc((size_t)NTOK * DM * 2);
  u16* xcb   = (u16*)alloc((size_t)NTOK * DM * 2);
  float* dtbc = (float*)alloc((size_t)NTOK * 1152 * 4);
  float* x2  = (float*)alloc((size_t)NTOK * DM * 4);
  float* hloc = (float*)alloc((size_t)4 * NCH * 1024 * 16 * 4);  // 8 MB
  float* hin  = (float*)alloc((size_t)4 * NCH * 1024 * 16 * 4);  // 8 MB
  float* sdtb = (float*)alloc((size_t)4 * NCH * 1024 * 4);       // 512 KB
  u16* yvb  = xm;        // reuse: xm dead after fused GEMM
  u16* xn2  = x1b;       // reuse: x1 dead after conv
  u16* hb   = xcb;       // reuse: xc+dtbc dead after scan

  const dim3 tb32(32, 8);
  // weight prep
  wtrans<<<dim3(32, 32), tb32, 0, stream>>>(w1_w, wv1T, 1024, 1024, 0, 1024);
  wtrans<<<dim3(32, 32), tb32, 0, stream>>>(v1_w, wv1T, 1024, 1024, 1024, 1024);
  wtrans<<<dim3(32, 32), tb32, 0, stream>>>(w2_w, w2T, 1024, 1024, 0, 1024);
  wtrans<<<dim3(32, 32), tb32, 0, stream>>>(dt_w, wcatT, 1024, 1024, 0, 1024);
  small_trans<<<64, 256, 0, stream>>>(Bp_w, Cp_w, wcatT);
  hipMemsetAsync(wcatT + (size_t)1056 * 1024, 0, (size_t)96 * 1024 * 2, stream);
  wtrans<<<dim3(96, 32), tb32, 0, stream>>>(ff1_w, ff1T, 1024, 3072, 0, 1024);
  wtrans<<<dim3(32, 96), tb32, 0, stream>>>(ff2_w, ff2T, 3072, 1024, 0, 3072);

  // LN1 -> LN2 -> xm (bf16)
  ln_ln_kernel<<<NTOK, 256, 0, stream>>>(x, ln1_g, ln1_b, ln_g, ln_b, xm);

  // fused: x1 = xm @ w1 + b ; v = silu(xm @ v1 + b)   (N=2048, 256x256 8-phase)
  gemm8p<5><<<256, 512, 0, stream>>>(xm, wv1T, w1_b, v1_b, x1b, vb, 1024, 1024, 8);

  // xc = silu(depthwise_conv(x1))
  conv_silu_kernel<<<(NTOK * DM) / (256 * 8), 256, 0, stream>>>(x1b, conv_w, xcb);

  // dtBC = [softplus(xc@dt_w+dt_b) | xc@Bp_w+Bp_b | xc@Cp_w+Cp_b | pad]  (f32, ld 1152)
  gemm_bt<4><<<576, 256, 0, stream>>>(xcb, wcatT, dt_b, Bp_b, Cp_b, nullptr,
                                      dtbc, nullptr, 1024, 1152, 9);

  // chunked selective scan fused with y*v -> yv (bf16)
  scan_pass1<<<2048, 256, 0, stream>>>(xcb, dtbc, A_log, hloc, sdtb);
  scan_pass2<<<256, 256, 0, stream>>>(A_log, sdtb, hloc, hin);
  scan_pass3<<<2048, 256, 0, stream>>>(xcb, dtbc, vb, A_log, D_p, hin, yvb);

  // x2 = yv @ w2 + b + x (f32)
  gemm_bt<3><<<512, 256, 0, stream>>>(yvb, w2T, w2_b, nullptr, nullptr, x,
                                      x2, nullptr, 1024, 1024, 8);

  // xn2 = LN(x2) (bf16)
  ln_kernel<<<NTOK, 256, 0, stream>>>(x2, ln2_g, ln2_b, xn2);

  // h = gelu(xn2 @ ff1 + b) (bf16, ld 3072, 256x256 8-phase)
  gemm8p<2><<<384, 512, 0, stream>>>(xn2, ff1T, ff1_b, nullptr, hb, nullptr,
                                     1024, 3072, 12);

  // out = h @ ff2 + b + x2 (f32)
  gemm_bt<3><<<512, 256, 0, stream>>>(hb, ff2T, ff2_b, nullptr, nullptr, x2,
                                      d_out, nullptr, 3072, 1024, 8);
}

// Round 6
// 460.484 us; speedup vs baseline: 1.2458x; 1.0324x over previous
//
#include <hip/hip_runtime.h>

typedef unsigned short u16;
typedef __attribute__((ext_vector_type(8))) short short8;
typedef __attribute__((ext_vector_type(4))) float f32x4;
typedef __attribute__((ext_vector_type(4))) unsigned short u16x4;

#define SEQ 2048
#define DM 1024
#define NTOK 8192  // B*L
#define CH 64      // scan chunk length
#define NCH 32     // SEQ / CH

__device__ __forceinline__ float b2f(u16 u) {
  union { float f; unsigned int i; } x; x.i = ((unsigned int)u) << 16; return x.f;
}
__device__ __forceinline__ u16 f2b(float f) {
  union { float f; unsigned int i; } x; x.f = f;
  unsigned int i = x.i;
  unsigned int r = (i + 0x7FFFu + ((i >> 16) & 1u)) >> 16;
  return (u16)r;
}

__device__ __forceinline__ void gload16(const u16* g, u16* l) {
  __builtin_amdgcn_global_load_lds(
      (const __attribute__((address_space(1))) void*)g,
      (__attribute__((address_space(3))) void*)l, 16, 0, 0);
}

// fast gelu (exact erf via Abramowitz-Stegun 7.1.26, |err| < 1.5e-7)
__device__ __forceinline__ float gelu_f(float v) {
  const float z = fabsf(v) * 0.70710678118f;
  const float t = __builtin_amdgcn_rcpf(1.f + 0.3275911f * z);
  float poly = ((((1.061405429f * t - 1.453152027f) * t + 1.421413741f) * t
                 - 0.284496736f) * t + 0.254829592f) * t;
  float e = 1.f - poly * __expf(-z * z);
  float erfv = (v < 0.f) ? -e : e;
  return 0.5f * v * (1.f + erfv);
}

// ---------------- weight transpose f32 (K x N) -> bf16 (N x K) ----------------
__global__ __launch_bounds__(256)
void wtrans(const float* __restrict__ in, u16* __restrict__ out,
            int K, int N, int rowOff, int ldOut)
{
  __shared__ float tile[32][33];
  const int n0 = blockIdx.x * 32;
  const int k0 = blockIdx.y * 32;
  const int tx = threadIdx.x, ty = threadIdx.y;
#pragma unroll
  for (int i = 0; i < 32; i += 8) {
    int k = k0 + ty + i, n = n0 + tx;
    tile[ty + i][tx] = (k < K && n < N) ? in[(long)k * N + n] : 0.f;
  }
  __syncthreads();
#pragma unroll
  for (int i = 0; i < 32; i += 8) {
    int n = n0 + ty + i, k = k0 + tx;
    if (n < N && k < K) out[(long)(rowOff + n) * ldOut + k] = f2b(tile[tx][ty + i]);
  }
}

// four 1024x1024 transposes in one launch (z-indexed)
__global__ __launch_bounds__(256)
void wtrans4(const float* __restrict__ s0, const float* __restrict__ s1,
             const float* __restrict__ s2, const float* __restrict__ s3,
             u16* __restrict__ d0, u16* __restrict__ d1,
             u16* __restrict__ d2, u16* __restrict__ d3)
{
  __shared__ float tile[32][33];
  const float* in; u16* out;
  switch (blockIdx.z) {
    case 0: in = s0; out = d0; break;
    case 1: in = s1; out = d1; break;
    case 2: in = s2; out = d2; break;
    default: in = s3; out = d3; break;
  }
  const int n0 = blockIdx.x * 32;
  const int k0 = blockIdx.y * 32;
  const int tx = threadIdx.x, ty = threadIdx.y;
#pragma unroll
  for (int i = 0; i < 32; i += 8)
    tile[ty + i][tx] = in[(long)(k0 + ty + i) * 1024 + n0 + tx];
  __syncthreads();
#pragma unroll
  for (int i = 0; i < 32; i += 8)
    out[(long)(n0 + ty + i) * 1024 + k0 + tx] = f2b(tile[tx][ty + i]);
}

// Bp_w/Cp_w (1024x16) -> rows [1024..1055] of WcatT (ld 1024); zero rows 1056..1151
__global__ __launch_bounds__(256)
void small_trans(const float* __restrict__ Bp, const float* __restrict__ Cp,
                 u16* __restrict__ wcatT)
{
  int t = blockIdx.x * 256 + threadIdx.x;  // 16384 threads
  int n = t >> 10, k = t & 1023;
  wcatT[(long)(1024 + n) * 1024 + k] = f2b(Bp[(long)k * 16 + n]);
  wcatT[(long)(1040 + n) * 1024 + k] = f2b(Cp[(long)k * 16 + n]);
#pragma unroll
  for (int i = 0; i < 6; ++i)
    wcatT[(long)1056 * 1024 + i * 16384 + t] = 0;
}

// ---------------- LayerNorm helpers ----------------
__device__ __forceinline__ void blockReduce2(float& a, float& b, float* s)
{
#pragma unroll
  for (int off = 32; off > 0; off >>= 1) {
    a += __shfl_xor(a, off);
    b += __shfl_xor(b, off);
  }
  const int lane = threadIdx.x & 63, wid = threadIdx.x >> 6;
  __syncthreads();
  if (lane == 0) { s[wid] = a; s[4 + wid] = b; }
  __syncthreads();
  a = s[0] + s[1] + s[2] + s[3];
  b = s[4] + s[5] + s[6] + s[7];
}

// fused LN1 -> LN2, f32 in, bf16 out (row length 1024, 256 thr x 4 elems)
__global__ __launch_bounds__(256)
void ln_ln_kernel(const float* __restrict__ x, const float* __restrict__ g1,
                  const float* __restrict__ b1, const float* __restrict__ g2,
                  const float* __restrict__ b2, u16* __restrict__ out)
{
  __shared__ float sred[8];
  const long row = blockIdx.x;
  const int t = threadIdx.x;
  const float4 xv = ((const float4*)(x + row * DM))[t];
  float s = xv.x + xv.y + xv.z + xv.w;
  float sq = xv.x * xv.x + xv.y * xv.y + xv.z * xv.z + xv.w * xv.w;
  blockReduce2(s, sq, sred);
  const float mu = s * (1.f / DM);
  const float rs = rsqrtf(sq * (1.f / DM) - mu * mu + 1e-5f);
  const float4 g1v = ((const float4*)g1)[t];
  const float4 b1v = ((const float4*)b1)[t];
  float xn[4];
  xn[0] = (xv.x - mu) * rs * g1v.x + b1v.x;
  xn[1] = (xv.y - mu) * rs * g1v.y + b1v.y;
  xn[2] = (xv.z - mu) * rs * g1v.z + b1v.z;
  xn[3] = (xv.w - mu) * rs * g1v.w + b1v.w;
  float s2 = xn[0] + xn[1] + xn[2] + xn[3];
  float sq2 = xn[0] * xn[0] + xn[1] * xn[1] + xn[2] * xn[2] + xn[3] * xn[3];
  blockReduce2(s2, sq2, sred);
  const float mu2 = s2 * (1.f / DM);
  const float rs2 = rsqrtf(sq2 * (1.f / DM) - mu2 * mu2 + 1e-5f);
  const float4 g2v = ((const float4*)g2)[t];
  const float4 b2v = ((const float4*)b2)[t];
  u16x4 o;
  o[0] = f2b((xn[0] - mu2) * rs2 * g2v.x + b2v.x);
  o[1] = f2b((xn[1] - mu2) * rs2 * g2v.y + b2v.y);
  o[2] = f2b((xn[2] - mu2) * rs2 * g2v.z + b2v.z);
  o[3] = f2b((xn[3] - mu2) * rs2 * g2v.w + b2v.w);
  *(u16x4*)(out + row * DM + t * 4) = o;
}

// single LN, f32 in, bf16 out
__global__ __launch_bounds__(256)
void ln_kernel(const float* __restrict__ x, const float* __restrict__ g,
               const float* __restrict__ b, u16* __restrict__ out)
{
  __shared__ float sred[8];
  const long row = blockIdx.x;
  const int t = threadIdx.x;
  const float4 xv = ((const float4*)(x + row * DM))[t];
  float s = xv.x + xv.y + xv.z + xv.w;
  float sq = xv.x * xv.x + xv.y * xv.y + xv.z * xv.z + xv.w * xv.w;
  blockReduce2(s, sq, sred);
  const float mu = s * (1.f / DM);
  const float rs = rsqrtf(sq * (1.f / DM) - mu * mu + 1e-5f);
  const float4 gv = ((const float4*)g)[t];
  const float4 bv = ((const float4*)b)[t];
  u16x4 o;
  o[0] = f2b((xv.x - mu) * rs * gv.x + bv.x);
  o[1] = f2b((xv.y - mu) * rs * gv.y + bv.y);
  o[2] = f2b((xv.z - mu) * rs * gv.z + bv.z);
  o[3] = f2b((xv.w - mu) * rs * gv.w + bv.w);
  *(u16x4*)(out + row * DM + t * 4) = o;
}

// ---------------- depthwise conv (k=3, pad 1 along L) + silu, vectorized ----------------
__global__ __launch_bounds__(256)
void conv_silu_kernel(const u16* __restrict__ x1, const float* __restrict__ w,
                      u16* __restrict__ xc)
{
  const long i8 = (long)blockIdx.x * 256 + threadIdx.x;  // NTOK*DM/8
  const long base = i8 * 8;
  const int d0 = (int)(base & (DM - 1));
  const long m = base >> 10;
  const int l = (int)(m & (SEQ - 1));
  const short8 cv = *(const short8*)(x1 + base);
  short8 lv = {}, rv = {};
  if (l > 0) lv = *(const short8*)(x1 + base - DM);
  if (l < SEQ - 1) rv = *(const short8*)(x1 + base + DM);
  short8 o;
#pragma unroll
  for (int j = 0; j < 8; ++j) {
    const int d = d0 + j;
    const float a = b2f((u16)lv[j]) * w[d * 3 + 0] + b2f((u16)cv[j]) * w[d * 3 + 1]
                  + b2f((u16)rv[j]) * w[d * 3 + 2];
    o[j] = (short)f2b(a / (1.f + __expf(-a)));
  }
  *(short8*)(xc + base) = o;
}

// ---------------- GEMM (R3-proven): 128x128, 2-buf, slot-XOR swizzle, XCD swizzle ----
// MODE 2: bf16 out = gelu(acc + bias)
// MODE 3: f32  out = acc + bias + resid
// MODE 4: dtBC: ld 1152 f32; col<1024 softplus(+bias); col<1040 +bias2; col<1056 +bias3
// MODE 5: fused w1|v1 (N=2048): col<1024 -> outp (bf16, +bias); else silu -> outp2 (+bias2)
template <int MODE>
__global__ __launch_bounds__(256)
void gemm_bt(const u16* __restrict__ A, const u16* __restrict__ BT,
             const float* __restrict__ bias, const float* __restrict__ bias2,
             const float* __restrict__ bias3, const float* __restrict__ resid,
             void* __restrict__ outp, void* __restrict__ outp2,
             int K, int ldOut, int nbx)
{
  __shared__ u16 lds_a[2][4096];
  __shared__ u16 lds_b[2][4096];
  const int t = threadIdx.x;
  const int lane = t & 63;
  const int wid = t >> 6;
  const int wr = wid >> 1, wc = wid & 1;

  int bid = blockIdx.x;
  const int qch = gridDim.x >> 3;
  bid = (bid & 7) * qch + (bid >> 3);
  const long brow = (long)(bid / nbx) * 128;
  const long bcol = (long)(bid % nbx) * 128;

  f32x4 acc[4][4] = {};

  const int srow = t >> 2;
  const int sslot = (t & 3) ^ ((t >> 3) & 3);
  const u16* aPtr = A + (brow + srow) * (long)K + sslot * 8;
  const u16* bPtr = BT + (bcol + srow) * (long)K + sslot * 8;
  u16* la = &lds_a[0][t * 8];
  u16* lb = &lds_b[0][t * 8];
  const long rowStep = 64L * K;
  const int nk = K >> 5;

  const int rslot = (lane >> 4) ^ ((lane >> 1) & 3);
  const int koff = rslot * 8;
  const int arow = wr * 64 + (lane & 15);
  const int brw = wc * 64 + (lane & 15);

#define STAGE(kt, buf)                                              \
  {                                                                 \
    const int k0_ = (kt) << 5;                                      \
    gload16(aPtr + k0_, la + (buf) * 4096);                         \
    gload16(aPtr + rowStep + k0_, la + (buf) * 4096 + 2048);        \
    gload16(bPtr + k0_, lb + (buf) * 4096);                         \
    gload16(bPtr + rowStep + k0_, lb + (buf) * 4096 + 2048);        \
  }

  STAGE(0, 0);
  __syncthreads();
  int cur = 0;
  for (int kt = 0; kt < nk; ++kt) {
    if (kt + 1 < nk) STAGE(kt + 1, cur ^ 1);
    short8 af[4], bfr[4];
#pragma unroll
    for (int m = 0; m < 4; ++m)
      af[m] = *(const short8*)&lds_a[cur][(arow + m * 16) * 32 + koff];
#pragma unroll
    for (int n = 0; n < 4; ++n)
      bfr[n] = *(const short8*)&lds_b[cur][(brw + n * 16) * 32 + koff];
#pragma unroll
    for (int m = 0; m < 4; ++m)
#pragma unroll
      for (int n = 0; n < 4; ++n)
        acc[m][n] = __builtin_amdgcn_mfma_f32_16x16x32_bf16(af[m], bfr[n], acc[m][n], 0, 0, 0);
    __syncthreads();
    cur ^= 1;
  }
#undef STAGE

  const int cc = lane & 15;
  const int r0 = (lane >> 4) * 4;
#pragma unroll
  for (int m = 0; m < 4; ++m) {
#pragma unroll
    for (int n = 0; n < 4; ++n) {
      const long col = bcol + wc * 64 + n * 16 + cc;
#pragma unroll
      for (int r = 0; r < 4; ++r) {
        const long row = brow + wr * 64 + m * 16 + r0 + r;
        float val = acc[m][n][r];
        if constexpr (MODE == 4) {
          if (col < 1024) {
            val += bias[col];
            val = (val > 20.f) ? val : log1pf(__expf(val));
            ((float*)outp)[row * 1152 + col] = val;
          } else if (col < 1040) {
            ((float*)outp)[row * 1152 + col] = val + bias2[col - 1024];
          } else if (col < 1056) {
            ((float*)outp)[row * 1152 + col] = val + bias3[col - 1040];
          }
        } else if constexpr (MODE == 5) {
          if (col < 1024) {
            val += bias[col];
            ((u16*)outp)[row * 1024 + col] = f2b(val);
          } else {
            val += bias2[col - 1024];
            val = val / (1.f + __expf(-val));
            ((u16*)outp2)[row * 1024 + col - 1024] = f2b(val);
          }
        } else {
          val += bias[col];
          if constexpr (MODE == 2) val = gelu_f(val);
          if constexpr (MODE == 3) {
            ((float*)outp)[row * ldOut + col] = val + resid[row * ldOut + col];
          } else {
            ((u16*)outp)[row * ldOut + col] = f2b(val);
          }
        }
      }
    }
  }
}

// ---------------- chunked selective scan ----------------
// pass 1: local scan (h0=0) computing h_out/chunk + sum(dt) + LOCAL OUTPUT
//   y_local[t] = C_t . h_local[t] + Dp*x[t]   and inclusive cumdt[t] (bf16)
__global__ __launch_bounds__(256)
void scan_pass1(const u16* __restrict__ xc, const float* __restrict__ dtbc,
                const float* __restrict__ A_log, const float* __restrict__ D_p,
                float* __restrict__ hloc, float* __restrict__ sdt,
                u16* __restrict__ ylb, u16* __restrict__ cdb)
{
  const int bx = blockIdx.x;
  const int b = bx >> 9;
  const int ch = (bx >> 4) & 31;
  const int dBase = (bx & 15) * 64;
  const int t = threadIdx.x;
  const int dl = t >> 2;
  const int q = t & 3;
  const int d = dBase + dl;

  __shared__ float s_bc[32][32];
  __shared__ float s_dt[32][64];
  __shared__ u16 s_x[32][64];
  __shared__ u16 s_yl[32][64];
  __shared__ u16 s_cd[32][64];

  float Areg[4];
#pragma unroll
  for (int j = 0; j < 4; ++j) Areg[j] = -__expf(A_log[d * 16 + q * 4 + j]);
  const float Dp = D_p[d];
  float h[4] = {0.f, 0.f, 0.f, 0.f};
  float sAcc = 0.f;
  const long mBase = (long)b * SEQ + ch * CH;

  for (int c0 = 0; c0 < CH; c0 += 32) {
#pragma unroll
    for (int i = 0; i < 4; ++i) {
      int idx = i * 256 + t;
      int s = idx >> 5, j = idx & 31;
      s_bc[s][j] = dtbc[(mBase + c0 + s) * 1152 + 1024 + j];
    }
#pragma unroll
    for (int i = 0; i < 8; ++i) {
      int idx = i * 256 + t;
      int s = idx >> 6, j = idx & 63;
      long m = mBase + c0 + s;
      s_dt[s][j] = dtbc[m * 1152 + dBase + j];
      s_x[s][j] = xc[m * DM + dBase + j];
    }
    __syncthreads();
#pragma unroll 4
    for (int s = 0; s < 32; ++s) {
      const float dt = s_dt[s][dl];
      const float xt = b2f(s_x[s][dl]);
      const float p = dt * xt;
      sAcc += dt;
      float y = 0.f;
#pragma unroll
      for (int j = 0; j < 4; ++j) {
        h[j] = __expf(dt * Areg[j]) * h[j] + p * s_bc[s][q * 4 + j];
        y = fmaf(h[j], s_bc[s][16 + q * 4 + j], y);
      }
      y += __shfl_xor(y, 1);
      y += __shfl_xor(y, 2);
      if (q == 0) s_yl[s][dl] = f2b(y + Dp * xt);
      if (q == 1) s_cd[s][dl] = f2b(sAcc);
    }
    __syncthreads();
#pragma unroll
    for (int i = 0; i < 8; ++i) {
      int idx = i * 256 + t;
      int s = idx >> 6, j = idx & 63;
      long m = mBase + c0 + s;
      ylb[m * DM + dBase + j] = s_yl[s][j];
      cdb[m * DM + dBase + j] = s_cd[s][j];
    }
    __syncthreads();
  }
  const long base = (((long)b * NCH + ch) * 1024 + d) * 16 + q * 4;
  float4 hv; hv.x = h[0]; hv.y = h[1]; hv.z = h[2]; hv.w = h[3];
  *(float4*)&hloc[base] = hv;
  if (q == 0) sdt[((long)b * NCH + ch) * 1024 + d] = sAcc;
}

// pass 2: sequential combine over chunks (unchanged)
__global__ __launch_bounds__(256)
void scan_pass2(const float* __restrict__ A_log, const float* __restrict__ sdt,
                const float* __restrict__ hloc, float* __restrict__ hin)
{
  const int tid = blockIdx.x * 256 + threadIdx.x;
  const int b = tid >> 14;
  const int dn = tid & 16383;
  const int d = dn >> 4;
  const float A = -__expf(A_log[dn]);
  float h = 0.f;
  for (int c = 0; c < NCH; ++c) {
    const long idx = (((long)b * NCH + c) << 14) + dn;
    hin[idx] = h;
    h = __expf(A * sdt[((long)b * NCH + c) * 1024 + d]) * h + hloc[idx];
  }
}

// pass 3 (parallel correction): yv = (y_local + sum_n C[t,n]*hin[n]*exp(A_n*cumdt)) * v
__global__ __launch_bounds__(256)
void scan_fix(const float* __restrict__ dtbc, const u16* __restrict__ ylb,
              const u16* __restrict__ cdb, const u16* __restrict__ vg,
              const float* __restrict__ A_log, const float* __restrict__ hin,
              u16* __restrict__ yv)
{
  const int bx = blockIdx.x;
  const int b = bx >> 9;
  const int ch = (bx >> 4) & 31;
  const int dBase = (bx & 15) * 64;
  const int t = threadIdx.x;
  const int dl = t >> 2;
  const int q = t & 3;
  const int d = dBase + dl;

  __shared__ float s_c[32][16];
  __shared__ u16 s_cd[32][64];
  __shared__ u16 s_yl[32][64];
  __shared__ u16 s_v[32][64];
  __shared__ u16 s_o[32][64];

  float Areg[4];
#pragma unroll
  for (int j = 0; j < 4; ++j) Areg[j] = -__expf(A_log[d * 16 + q * 4 + j]);
  const float4 hv4 = *(const float4*)&hin[(((long)b * NCH + ch) * 1024 + d) * 16 + q * 4];
  const float hv[4] = {hv4.x, hv4.y, hv4.z, hv4.w};

  const long mBase = (long)b * SEQ + ch * CH;

  for (int c0 = 0; c0 < CH; c0 += 32) {
#pragma unroll
    for (int i = 0; i < 2; ++i) {
      int idx = i * 256 + t;
      int s = idx >> 4, j = idx & 15;
      s_c[s][j] = dtbc[(mBase + c0 + s) * 1152 + 1040 + j];
    }
#pragma unroll
    for (int i = 0; i < 8; ++i) {
      int idx = i * 256 + t;
      int s = idx >> 6, j = idx & 63;
      long m = mBase + c0 + s;
      s_cd[s][j] = cdb[m * DM + dBase + j];
      s_yl[s][j] = ylb[m * DM + dBase + j];
      s_v[s][j] = vg[m * DM + dBase + j];
    }
    __syncthreads();
#pragma unroll 4
    for (int s = 0; s < 32; ++s) {
      const float cd = b2f(s_cd[s][dl]);
      float corr = 0.f;
#pragma unroll
      for (int j = 0; j < 4; ++j)
        corr = fmaf(s_c[s][q * 4 + j] * hv[j], __expf(Areg[j] * cd), corr);
      corr += __shfl_xor(corr, 1);
      corr += __shfl_xor(corr, 2);
      if (q == 0)
        s_o[s][dl] = f2b((b2f(s_yl[s][dl]) + corr) * b2f(s_v[s][dl]));
    }
    __syncthreads();
#pragma unroll
    for (int i = 0; i < 8; ++i) {
      int idx = i * 256 + t;
      int s = idx >> 6, j = idx & 63;
      yv[(mBase + c0 + s) * DM + dBase + j] = s_o[s][j];
    }
    __syncthreads();
  }
}

extern "C" void kernel_launch(void* const* d_in, const int* in_sizes, int n_in,
                              void* d_out, int out_size, void* d_ws, size_t ws_size,
                              hipStream_t stream)
{
  (void)in_sizes; (void)n_in; (void)out_size; (void)ws_size;
  const float* x      = (const float*)d_in[0];
  const float* ln1_g  = (const float*)d_in[1];
  const float* ln1_b  = (const float*)d_in[2];
  const float* ln_g   = (const float*)d_in[3];
  const float* ln_b   = (const float*)d_in[4];
  const float* w1_w   = (const float*)d_in[5];
  const float* w1_b   = (const float*)d_in[6];
  const float* v1_w   = (const float*)d_in[7];
  const float* v1_b   = (const float*)d_in[8];
  const float* w2_w   = (const float*)d_in[9];
  const float* w2_b   = (const float*)d_in[10];
  const float* conv_w = (const float*)d_in[11];
  const float* dt_w   = (const float*)d_in[12];
  const float* dt_b   = (const float*)d_in[13];
  const float* Bp_w   = (const float*)d_in[14];
  const float* Bp_b   = (const float*)d_in[15];
  const float* Cp_w   = (const float*)d_in[16];
  const float* Cp_b   = (const float*)d_in[17];
  const float* A_log  = (const float*)d_in[18];
  const float* D_p    = (const float*)d_in[19];
  const float* ln2_g  = (const float*)d_in[20];
  const float* ln2_b  = (const float*)d_in[21];
  const float* ff1_w  = (const float*)d_in[22];
  const float* ff1_b  = (const float*)d_in[23];
  const float* ff2_w  = (const float*)d_in[24];
  const float* ff2_b  = (const float*)d_in[25];

  char* ws = (char*)d_ws;
  size_t cur = 0;
  auto alloc = [&](size_t bytes) -> void* {
    void* p = ws + cur;
    cur = (cur + bytes + 255) & ~(size_t)255;
    return p;
  };

  u16* wv1T  = (u16*)alloc((size_t)2048 * 1024 * 2);   // [w1T ; v1T]
  u16* w2T   = (u16*)alloc((size_t)1024 * 1024 * 2);
  u16* wcatT = (u16*)alloc((size_t)1152 * 1024 * 2);
  u16* ff1T  = (u16*)alloc((size_t)3072 * 1024 * 2);
  u16* ff2T  = (u16*)alloc((size_t)1024 * 3072 * 2);
  u16* xm    = (u16*)alloc((size_t)NTOK * DM * 2);
  u16* x1b   = (u16*)alloc((size_t)NTOK * DM * 2);
  u16* vb    = (u16*)alloc((size_t)NTOK * DM * 2);
  u16* xcb   = (u16*)alloc((size_t)NTOK * DM * 2);
  float* dtbc = (float*)alloc((size_t)NTOK * 1152 * 4);
  float* x2  = (float*)alloc((size_t)NTOK * DM * 4);
  float* hloc = (float*)alloc((size_t)4 * NCH * 1024 * 16 * 4);  // 8 MB
  float* hin  = (float*)alloc((size_t)4 * NCH * 1024 * 16 * 4);  // 8 MB
  float* sdtb = (float*)alloc((size_t)4 * NCH * 1024 * 4);       // 512 KB
  u16* yvb  = xm;          // reuse: xm dead after fused GEMM
  u16* xn2  = x1b;         // reuse: x1 dead after conv (ln writes AFTER scan_fix reads ylb)
  u16* ylb  = x1b;         // reuse: x1 dead after conv; ylb dead before xn2 written
  u16* cdb  = (u16*)x2;    // reuse: x2 written only after scan_fix consumed cdb
  u16* hb   = xcb;         // reuse: xc+dtbc dead after scan

  const dim3 tb32(32, 8);
  // weight prep
  wtrans4<<<dim3(32, 32, 4), tb32, 0, stream>>>(w1_w, v1_w, w2_w, dt_w,
                                                wv1T, wv1T + (size_t)1024 * 1024,
                                                w2T, wcatT);
  small_trans<<<64, 256, 0, stream>>>(Bp_w, Cp_w, wcatT);
  wtrans<<<dim3(96, 32), tb32, 0, stream>>>(ff1_w, ff1T, 1024, 3072, 0, 1024);
  wtrans<<<dim3(32, 96), tb32, 0, stream>>>(ff2_w, ff2T, 3072, 1024, 0, 3072);

  // LN1 -> LN2 -> xm (bf16)
  ln_ln_kernel<<<NTOK, 256, 0, stream>>>(x, ln1_g, ln1_b, ln_g, ln_b, xm);

  // fused: x1 = xm @ w1 + b ; v = silu(xm @ v1 + b)   (N=2048)
  gemm_bt<5><<<1024, 256, 0, stream>>>(xm, wv1T, w1_b, v1_b, nullptr, nullptr,
                                       x1b, vb, 1024, 1024, 16);

  // xc = silu(depthwise_conv(x1))
  conv_silu_kernel<<<(NTOK * DM) / (256 * 8), 256, 0, stream>>>(x1b, conv_w, xcb);

  // dtBC = [softplus(xc@dt_w+dt_b) | xc@Bp_w+Bp_b | xc@Cp_w+Cp_b | pad]  (f32, ld 1152)
  gemm_bt<4><<<576, 256, 0, stream>>>(xcb, wcatT, dt_b, Bp_b, Cp_b, nullptr,
                                      dtbc, nullptr, 1024, 1152, 9);

  // chunked selective scan: local scan (+ y_local, cumdt) -> combine -> parallel fix
  scan_pass1<<<2048, 256, 0, stream>>>(xcb, dtbc, A_log, D_p, hloc, sdtb, ylb, cdb);
  scan_pass2<<<256, 256, 0, stream>>>(A_log, sdtb, hloc, hin);
  scan_fix<<<2048, 256, 0, stream>>>(dtbc, ylb, cdb, vb, A_log, hin, yvb);

  // x2 = yv @ w2 + b + x (f32)
  gemm_bt<3><<<512, 256, 0, stream>>>(yvb, w2T, w2_b, nullptr, nullptr, x,
                                      x2, nullptr, 1024, 1024, 8);

  // xn2 = LN(x2) (bf16)
  ln_kernel<<<NTOK, 256, 0, stream>>>(x2, ln2_g, ln2_b, xn2);

  // h = gelu(xn2 @ ff1 + b) (bf16, ld 3072)
  gemm_bt<2><<<1536, 256, 0, stream>>>(xn2, ff1T, ff1_b, nullptr, nullptr, nullptr,
                                       hb, nullptr, 1024, 3072, 24);

  // out = h @ ff2 + b + x2 (f32)
  gemm_bt<3><<<512, 256, 0, stream>>>(hb, ff2T, ff2_b, nullptr, nullptr, x2,
                                      d_out, nullptr, 3072, 1024, 8);
}

// Round 7
// 438.793 us; speedup vs baseline: 1.3074x; 1.0494x over previous
//
#include <hip/hip_runtime.h>

typedef unsigned short u16;
typedef __attribute__((ext_vector_type(8))) short short8;
typedef __attribute__((ext_vector_type(4))) float f32x4;
typedef __attribute__((ext_vector_type(4))) unsigned short u16x4;

#define SEQ 2048
#define DM 1024
#define NTOK 8192  // B*L
#define CH 64      // scan chunk length
#define NCH 32     // SEQ / CH

__device__ __forceinline__ float b2f(u16 u) {
  union { float f; unsigned int i; } x; x.i = ((unsigned int)u) << 16; return x.f;
}
__device__ __forceinline__ u16 f2b(float f) {
  union { float f; unsigned int i; } x; x.f = f;
  unsigned int i = x.i;
  unsigned int r = (i + 0x7FFFu + ((i >> 16) & 1u)) >> 16;
  return (u16)r;
}

__device__ __forceinline__ void gload16(const u16* g, u16* l) {
  __builtin_amdgcn_global_load_lds(
      (const __attribute__((address_space(1))) void*)g,
      (__attribute__((address_space(3))) void*)l, 16, 0, 0);
}

// fast gelu (exact erf via Abramowitz-Stegun 7.1.26, |err| < 1.5e-7)
__device__ __forceinline__ float gelu_f(float v) {
  const float z = fabsf(v) * 0.70710678118f;
  const float t = __builtin_amdgcn_rcpf(1.f + 0.3275911f * z);
  float poly = ((((1.061405429f * t - 1.453152027f) * t + 1.421413741f) * t
                 - 0.284496736f) * t + 0.254829592f) * t;
  float e = 1.f - poly * __expf(-z * z);
  float erfv = (v < 0.f) ? -e : e;
  return 0.5f * v * (1.f + erfv);
}
__device__ __forceinline__ float silu_f(float v) {
  return v * __builtin_amdgcn_rcpf(1.f + __expf(-v));
}
// stable softplus via hw exp/log
__device__ __forceinline__ float softplus_f(float v) {
  return fmaxf(v, 0.f) + __logf(1.f + __expf(-fabsf(v)));
}

// ---------------- weight transpose f32 (K x N) -> bf16 (N x K) ----------------
__global__ __launch_bounds__(256)
void wtrans(const float* __restrict__ in, u16* __restrict__ out,
            int K, int N, int rowOff, int ldOut)
{
  __shared__ float tile[32][33];
  const int n0 = blockIdx.x * 32;
  const int k0 = blockIdx.y * 32;
  const int tx = threadIdx.x, ty = threadIdx.y;
#pragma unroll
  for (int i = 0; i < 32; i += 8) {
    int k = k0 + ty + i, n = n0 + tx;
    tile[ty + i][tx] = (k < K && n < N) ? in[(long)k * N + n] : 0.f;
  }
  __syncthreads();
#pragma unroll
  for (int i = 0; i < 32; i += 8) {
    int n = n0 + ty + i, k = k0 + tx;
    if (n < N && k < K) out[(long)(rowOff + n) * ldOut + k] = f2b(tile[tx][ty + i]);
  }
}

// four 1024x1024 transposes in one launch (z-indexed)
__global__ __launch_bounds__(256)
void wtrans4(const float* __restrict__ s0, const float* __restrict__ s1,
             const float* __restrict__ s2, const float* __restrict__ s3,
             u16* __restrict__ d0, u16* __restrict__ d1,
             u16* __restrict__ d2, u16* __restrict__ d3)
{
  __shared__ float tile[32][33];
  const float* in; u16* out;
  switch (blockIdx.z) {
    case 0: in = s0; out = d0; break;
    case 1: in = s1; out = d1; break;
    case 2: in = s2; out = d2; break;
    default: in = s3; out = d3; break;
  }
  const int n0 = blockIdx.x * 32;
  const int k0 = blockIdx.y * 32;
  const int tx = threadIdx.x, ty = threadIdx.y;
#pragma unroll
  for (int i = 0; i < 32; i += 8)
    tile[ty + i][tx] = in[(long)(k0 + ty + i) * 1024 + n0 + tx];
  __syncthreads();
#pragma unroll
  for (int i = 0; i < 32; i += 8)
    out[(long)(n0 + ty + i) * 1024 + k0 + tx] = f2b(tile[tx][ty + i]);
}

// Bp_w/Cp_w (1024x16) -> rows [1024..1055] of WcatT (ld 1024); zero rows 1056..1151
__global__ __launch_bounds__(256)
void small_trans(const float* __restrict__ Bp, const float* __restrict__ Cp,
                 u16* __restrict__ wcatT)
{
  int t = blockIdx.x * 256 + threadIdx.x;  // 16384 threads
  int n = t >> 10, k = t & 1023;
  wcatT[(long)(1024 + n) * 1024 + k] = f2b(Bp[(long)k * 16 + n]);
  wcatT[(long)(1040 + n) * 1024 + k] = f2b(Cp[(long)k * 16 + n]);
#pragma unroll
  for (int i = 0; i < 6; ++i)
    wcatT[(long)1056 * 1024 + i * 16384 + t] = 0;
}

// ---------------- LayerNorm helpers ----------------
__device__ __forceinline__ void blockReduce2(float& a, float& b, float* s)
{
#pragma unroll
  for (int off = 32; off > 0; off >>= 1) {
    a += __shfl_xor(a, off);
    b += __shfl_xor(b, off);
  }
  const int lane = threadIdx.x & 63, wid = threadIdx.x >> 6;
  __syncthreads();
  if (lane == 0) { s[wid] = a; s[4 + wid] = b; }
  __syncthreads();
  a = s[0] + s[1] + s[2] + s[3];
  b = s[4] + s[5] + s[6] + s[7];
}

// fused LN1 -> LN2, f32 in, bf16 out (row length 1024, 256 thr x 4 elems)
__global__ __launch_bounds__(256)
void ln_ln_kernel(const float* __restrict__ x, const float* __restrict__ g1,
                  const float* __restrict__ b1, const float* __restrict__ g2,
                  const float* __restrict__ b2, u16* __restrict__ out)
{
  __shared__ float sred[8];
  const long row = blockIdx.x;
  const int t = threadIdx.x;
  const float4 xv = ((const float4*)(x + row * DM))[t];
  float s = xv.x + xv.y + xv.z + xv.w;
  float sq = xv.x * xv.x + xv.y * xv.y + xv.z * xv.z + xv.w * xv.w;
  blockReduce2(s, sq, sred);
  const float mu = s * (1.f / DM);
  const float rs = rsqrtf(sq * (1.f / DM) - mu * mu + 1e-5f);
  const float4 g1v = ((const float4*)g1)[t];
  const float4 b1v = ((const float4*)b1)[t];
  float xn[4];
  xn[0] = (xv.x - mu) * rs * g1v.x + b1v.x;
  xn[1] = (xv.y - mu) * rs * g1v.y + b1v.y;
  xn[2] = (xv.z - mu) * rs * g1v.z + b1v.z;
  xn[3] = (xv.w - mu) * rs * g1v.w + b1v.w;
  float s2 = xn[0] + xn[1] + xn[2] + xn[3];
  float sq2 = xn[0] * xn[0] + xn[1] * xn[1] + xn[2] * xn[2] + xn[3] * xn[3];
  blockReduce2(s2, sq2, sred);
  const float mu2 = s2 * (1.f / DM);
  const float rs2 = rsqrtf(sq2 * (1.f / DM) - mu2 * mu2 + 1e-5f);
  const float4 g2v = ((const float4*)g2)[t];
  const float4 b2v = ((const float4*)b2)[t];
  u16x4 o;
  o[0] = f2b((xn[0] - mu2) * rs2 * g2v.x + b2v.x);
  o[1] = f2b((xn[1] - mu2) * rs2 * g2v.y + b2v.y);
  o[2] = f2b((xn[2] - mu2) * rs2 * g2v.z + b2v.z);
  o[3] = f2b((xn[3] - mu2) * rs2 * g2v.w + b2v.w);
  *(u16x4*)(out + row * DM + t * 4) = o;
}

// single LN, f32 in, bf16 out
__global__ __launch_bounds__(256)
void ln_kernel(const float* __restrict__ x, const float* __restrict__ g,
               const float* __restrict__ b, u16* __restrict__ out)
{
  __shared__ float sred[8];
  const long row = blockIdx.x;
  const int t = threadIdx.x;
  const float4 xv = ((const float4*)(x + row * DM))[t];
  float s = xv.x + xv.y + xv.z + xv.w;
  float sq = xv.x * xv.x + xv.y * xv.y + xv.z * xv.z + xv.w * xv.w;
  blockReduce2(s, sq, sred);
  const float mu = s * (1.f / DM);
  const float rs = rsqrtf(sq * (1.f / DM) - mu * mu + 1e-5f);
  const float4 gv = ((const float4*)g)[t];
  const float4 bv = ((const float4*)b)[t];
  u16x4 o;
  o[0] = f2b((xv.x - mu) * rs * gv.x + bv.x);
  o[1] = f2b((xv.y - mu) * rs * gv.y + bv.y);
  o[2] = f2b((xv.z - mu) * rs * gv.z + bv.z);
  o[3] = f2b((xv.w - mu) * rs * gv.w + bv.w);
  *(u16x4*)(out + row * DM + t * 4) = o;
}

// ---------------- depthwise conv (k=3, pad 1 along L) + silu, vectorized ----------------
__global__ __launch_bounds__(256)
void conv_silu_kernel(const u16* __restrict__ x1, const float* __restrict__ w,
                      u16* __restrict__ xc)
{
  const long i8 = (long)blockIdx.x * 256 + threadIdx.x;  // NTOK*DM/8
  const long base = i8 * 8;
  const int d0 = (int)(base & (DM - 1));
  const long m = base >> 10;
  const int l = (int)(m & (SEQ - 1));
  const short8 cv = *(const short8*)(x1 + base);
  short8 lv = {}, rv = {};
  if (l > 0) lv = *(const short8*)(x1 + base - DM);
  if (l < SEQ - 1) rv = *(const short8*)(x1 + base + DM);
  short8 o;
#pragma unroll
  for (int j = 0; j < 8; ++j) {
    const int d = d0 + j;
    const float a = b2f((u16)lv[j]) * w[d * 3 + 0] + b2f((u16)cv[j]) * w[d * 3 + 1]
                  + b2f((u16)rv[j]) * w[d * 3 + 2];
    o[j] = (short)f2b(silu_f(a));
  }
  *(short8*)(xc + base) = o;
}

// ---------------- GEMM: 128xBN tile, 2-buf, slot-XOR swizzle, XCD swizzle ----------
// BN in {128, 64}. BN=64 doubles grid for grid-starved GEMMs (more TLP).
// MODE 2: bf16 out = gelu(acc + bias)
// MODE 3: f32  out = acc + bias + resid
// MODE 4: dtBC: ld 1152 f32; col<1024 softplus(+bias); col<1040 +bias2; col<1056 +bias3
// MODE 5: fused w1|v1 (N=2048): col<1024 -> outp (bf16, +bias); else silu -> outp2 (+bias2)
template <int MODE, int BN>
__global__ __launch_bounds__(256)
void gemm_bt(const u16* __restrict__ A, const u16* __restrict__ BT,
             const float* __restrict__ bias, const float* __restrict__ bias2,
             const float* __restrict__ bias3, const float* __restrict__ resid,
             void* __restrict__ outp, void* __restrict__ outp2,
             int K, int ldOut, int nbx)
{
  constexpr int NF = BN / 32;            // B col fragments per wave: 4 or 2
  constexpr int BSZ = BN * 32;           // u16 per B buffer
  __shared__ u16 lds_a[2][4096];
  __shared__ u16 lds_b[2][BSZ];
  const int t = threadIdx.x;
  const int lane = t & 63;
  const int wid = t >> 6;
  const int wr = wid >> 1, wc = wid & 1;

  int bid = blockIdx.x;
  const int qch = gridDim.x >> 3;
  bid = (bid & 7) * qch + (bid >> 3);
  const long brow = (long)(bid / nbx) * 128;
  const long bcol = (long)(bid % nbx) * BN;

  f32x4 acc[4][NF] = {};

  const int srow = t >> 2;
  const int sslot = (t & 3) ^ ((t >> 3) & 3);
  const u16* aPtr = A + (brow + srow) * (long)K + sslot * 8;
  const u16* bPtr = BT + (bcol + srow) * (long)K + sslot * 8;
  u16* la = &lds_a[0][t * 8];
  u16* lb = &lds_b[0][t * 8];
  const long rowStep = 64L * K;
  const int nk = K >> 5;

  const int rslot = (lane >> 4) ^ ((lane >> 1) & 3);
  const int koff = rslot * 8;
  const int arow = wr * 64 + (lane & 15);
  const int brw = (BN == 128 ? wc * 64 : wc * 32) + (lane & 15);

#define STAGE(kt, buf)                                                  \
  {                                                                     \
    const int k0_ = (kt) << 5;                                          \
    gload16(aPtr + k0_, la + (buf) * 4096);                             \
    gload16(aPtr + rowStep + k0_, la + (buf) * 4096 + 2048);            \
    gload16(bPtr + k0_, lb + (buf) * BSZ);                              \
    if constexpr (BN == 128)                                            \
      gload16(bPtr + rowStep + k0_, lb + (buf) * BSZ + 2048);           \
  }

  STAGE(0, 0);
  __syncthreads();
  int cur = 0;
  for (int kt = 0; kt < nk; ++kt) {
    if (kt + 1 < nk) STAGE(kt + 1, cur ^ 1);
    short8 af[4], bfr[NF];
#pragma unroll
    for (int m = 0; m < 4; ++m)
      af[m] = *(const short8*)&lds_a[cur][(arow + m * 16) * 32 + koff];
#pragma unroll
    for (int n = 0; n < NF; ++n)
      bfr[n] = *(const short8*)&lds_b[cur][(brw + n * 16) * 32 + koff];
#pragma unroll
    for (int m = 0; m < 4; ++m)
#pragma unroll
      for (int n = 0; n < NF; ++n)
        acc[m][n] = __builtin_amdgcn_mfma_f32_16x16x32_bf16(af[m], bfr[n], acc[m][n], 0, 0, 0);
    __syncthreads();
    cur ^= 1;
  }
#undef STAGE

  const int cc = lane & 15;
  const int r0 = (lane >> 4) * 4;
#pragma unroll
  for (int m = 0; m < 4; ++m) {
#pragma unroll
    for (int n = 0; n < NF; ++n) {
      const long col = bcol + (BN == 128 ? wc * 64 : wc * 32) + n * 16 + cc;
#pragma unroll
      for (int r = 0; r < 4; ++r) {
        const long row = brow + wr * 64 + m * 16 + r0 + r;
        float val = acc[m][n][r];
        if constexpr (MODE == 4) {
          if (col < 1024) {
            ((float*)outp)[row * 1152 + col] = softplus_f(val + bias[col]);
          } else if (col < 1040) {
            ((float*)outp)[row * 1152 + col] = val + bias2[col - 1024];
          } else if (col < 1056) {
            ((float*)outp)[row * 1152 + col] = val + bias3[col - 1040];
          }
        } else if constexpr (MODE == 5) {
          if (col < 1024) {
            val += bias[col];
            ((u16*)outp)[row * 1024 + col] = f2b(val);
          } else {
            ((u16*)outp2)[row * 1024 + col - 1024] = f2b(silu_f(val + bias2[col - 1024]));
          }
        } else {
          val += bias[col];
          if constexpr (MODE == 2) val = gelu_f(val);
          if constexpr (MODE == 3) {
            ((float*)outp)[row * ldOut + col] = val + resid[row * ldOut + col];
          } else {
            ((u16*)outp)[row * ldOut + col] = f2b(val);
          }
        }
      }
    }
  }
}

// ---------------- chunked selective scan ----------------
// pass 1: local scan (h0=0) computing h_out/chunk + sum(dt) + LOCAL OUTPUT
//   y_local[t] = C_t . h_local[t] + Dp*x[t]   and inclusive cumdt[t] (bf16)
__global__ __launch_bounds__(256)
void scan_pass1(const u16* __restrict__ xc, const float* __restrict__ dtbc,
                const float* __restrict__ A_log, const float* __restrict__ D_p,
                float* __restrict__ hloc, float* __restrict__ sdt,
                u16* __restrict__ ylb, u16* __restrict__ cdb)
{
  const int bx = blockIdx.x;
  const int b = bx >> 9;
  const int ch = (bx >> 4) & 31;
  const int dBase = (bx & 15) * 64;
  const int t = threadIdx.x;
  const int dl = t >> 2;
  const int q = t & 3;
  const int d = dBase + dl;

  __shared__ float s_bc[32][32];
  __shared__ float s_dt[32][64];
  __shared__ u16 s_x[32][64];
  __shared__ u16 s_yl[32][64];
  __shared__ u16 s_cd[32][64];

  float Areg[4];
#pragma unroll
  for (int j = 0; j < 4; ++j) Areg[j] = -__expf(A_log[d * 16 + q * 4 + j]);
  const float Dp = D_p[d];
  float h[4] = {0.f, 0.f, 0.f, 0.f};
  float sAcc = 0.f;
  const long mBase = (long)b * SEQ + ch * CH;

  for (int c0 = 0; c0 < CH; c0 += 32) {
#pragma unroll
    for (int i = 0; i < 4; ++i) {
      int idx = i * 256 + t;
      int s = idx >> 5, j = idx & 31;
      s_bc[s][j] = dtbc[(mBase + c0 + s) * 1152 + 1024 + j];
    }
#pragma unroll
    for (int i = 0; i < 8; ++i) {
      int idx = i * 256 + t;
      int s = idx >> 6, j = idx & 63;
      long m = mBase + c0 + s;
      s_dt[s][j] = dtbc[m * 1152 + dBase + j];
      s_x[s][j] = xc[m * DM + dBase + j];
    }
    __syncthreads();
#pragma unroll 4
    for (int s = 0; s < 32; ++s) {
      const float dt = s_dt[s][dl];
      const float xt = b2f(s_x[s][dl]);
      const float p = dt * xt;
      sAcc += dt;
      float y = 0.f;
#pragma unroll
      for (int j = 0; j < 4; ++j) {
        h[j] = __expf(dt * Areg[j]) * h[j] + p * s_bc[s][q * 4 + j];
        y = fmaf(h[j], s_bc[s][16 + q * 4 + j], y);
      }
      y += __shfl_xor(y, 1);
      y += __shfl_xor(y, 2);
      if (q == 0) s_yl[s][dl] = f2b(y + Dp * xt);
      if (q == 1) s_cd[s][dl] = f2b(sAcc);
    }
    __syncthreads();
#pragma unroll
    for (int i = 0; i < 8; ++i) {
      int idx = i * 256 + t;
      int s = idx >> 6, j = idx & 63;
      long m = mBase + c0 + s;
      ylb[m * DM + dBase + j] = s_yl[s][j];
      cdb[m * DM + dBase + j] = s_cd[s][j];
    }
    __syncthreads();
  }
  const long base = (((long)b * NCH + ch) * 1024 + d) * 16 + q * 4;
  float4 hv; hv.x = h[0]; hv.y = h[1]; hv.z = h[2]; hv.w = h[3];
  *(float4*)&hloc[base] = hv;
  if (q == 0) sdt[((long)b * NCH + ch) * 1024 + d] = sAcc;
}

// pass 2: sequential combine over chunks
__global__ __launch_bounds__(256)
void scan_pass2(const float* __restrict__ A_log, const float* __restrict__ sdt,
                const float* __restrict__ hloc, float* __restrict__ hin)
{
  const int tid = blockIdx.x * 256 + threadIdx.x;
  const int b = tid >> 14;
  const int dn = tid & 16383;
  const int d = dn >> 4;
  const float A = -__expf(A_log[dn]);
  float h = 0.f;
  for (int c = 0; c < NCH; ++c) {
    const long idx = (((long)b * NCH + c) << 14) + dn;
    hin[idx] = h;
    h = __expf(A * sdt[((long)b * NCH + c) * 1024 + d]) * h + hloc[idx];
  }
}

// pass 3 (parallel correction): yv = (y_local + sum_n C[t,n]*hin[n]*exp(A_n*cumdt)) * v
__global__ __launch_bounds__(256)
void scan_fix(const float* __restrict__ dtbc, const u16* __restrict__ ylb,
              const u16* __restrict__ cdb, const u16* __restrict__ vg,
              const float* __restrict__ A_log, const float* __restrict__ hin,
              u16* __restrict__ yv)
{
  const int bx = blockIdx.x;
  const int b = bx >> 9;
  const int ch = (bx >> 4) & 31;
  const int dBase = (bx & 15) * 64;
  const int t = threadIdx.x;
  const int dl = t >> 2;
  const int q = t & 3;
  const int d = dBase + dl;

  __shared__ float s_c[32][16];
  __shared__ u16 s_cd[32][64];
  __shared__ u16 s_yl[32][64];
  __shared__ u16 s_v[32][64];
  __shared__ u16 s_o[32][64];

  float Areg[4];
#pragma unroll
  for (int j = 0; j < 4; ++j) Areg[j] = -__expf(A_log[d * 16 + q * 4 + j]);
  const float4 hv4 = *(const float4*)&hin[(((long)b * NCH + ch) * 1024 + d) * 16 + q * 4];
  const float hv[4] = {hv4.x, hv4.y, hv4.z, hv4.w};

  const long mBase = (long)b * SEQ + ch * CH;

  for (int c0 = 0; c0 < CH; c0 += 32) {
#pragma unroll
    for (int i = 0; i < 2; ++i) {
      int idx = i * 256 + t;
      int s = idx >> 4, j = idx & 15;
      s_c[s][j] = dtbc[(mBase + c0 + s) * 1152 + 1040 + j];
    }
#pragma unroll
    for (int i = 0; i < 8; ++i) {
      int idx = i * 256 + t;
      int s = idx >> 6, j = idx & 63;
      long m = mBase + c0 + s;
      s_cd[s][j] = cdb[m * DM + dBase + j];
      s_yl[s][j] = ylb[m * DM + dBase + j];
      s_v[s][j] = vg[m * DM + dBase + j];
    }
    __syncthreads();
#pragma unroll 4
    for (int s = 0; s < 32; ++s) {
      const float cd = b2f(s_cd[s][dl]);
      float corr = 0.f;
#pragma unroll
      for (int j = 0; j < 4; ++j)
        corr = fmaf(s_c[s][q * 4 + j] * hv[j], __expf(Areg[j] * cd), corr);
      corr += __shfl_xor(corr, 1);
      corr += __shfl_xor(corr, 2);
      if (q == 0)
        s_o[s][dl] = f2b((b2f(s_yl[s][dl]) + corr) * b2f(s_v[s][dl]));
    }
    __syncthreads();
#pragma unroll
    for (int i = 0; i < 8; ++i) {
      int idx = i * 256 + t;
      int s = idx >> 6, j = idx & 63;
      yv[(mBase + c0 + s) * DM + dBase + j] = s_o[s][j];
    }
    __syncthreads();
  }
}

extern "C" void kernel_launch(void* const* d_in, const int* in_sizes, int n_in,
                              void* d_out, int out_size, void* d_ws, size_t ws_size,
                              hipStream_t stream)
{
  (void)in_sizes; (void)n_in; (void)out_size; (void)ws_size;
  const float* x      = (const float*)d_in[0];
  const float* ln1_g  = (const float*)d_in[1];
  const float* ln1_b  = (const float*)d_in[2];
  const float* ln_g   = (const float*)d_in[3];
  const float* ln_b   = (const float*)d_in[4];
  const float* w1_w   = (const float*)d_in[5];
  const float* w1_b   = (const float*)d_in[6];
  const float* v1_w   = (const float*)d_in[7];
  const float* v1_b   = (const float*)d_in[8];
  const float* w2_w   = (const float*)d_in[9];
  const float* w2_b   = (const float*)d_in[10];
  const float* conv_w = (const float*)d_in[11];
  const float* dt_w   = (const float*)d_in[12];
  const float* dt_b   = (const float*)d_in[13];
  const float* Bp_w   = (const float*)d_in[14];
  const float* Bp_b   = (const float*)d_in[15];
  const float* Cp_w   = (const float*)d_in[16];
  const float* Cp_b   = (const float*)d_in[17];
  const float* A_log  = (const float*)d_in[18];
  const float* D_p    = (const float*)d_in[19];
  const float* ln2_g  = (const float*)d_in[20];
  const float* ln2_b  = (const float*)d_in[21];
  const float* ff1_w  = (const float*)d_in[22];
  const float* ff1_b  = (const float*)d_in[23];
  const float* ff2_w  = (const float*)d_in[24];
  const float* ff2_b  = (const float*)d_in[25];

  char* ws = (char*)d_ws;
  size_t cur = 0;
  auto alloc = [&](size_t bytes) -> void* {
    void* p = ws + cur;
    cur = (cur + bytes + 255) & ~(size_t)255;
    return p;
  };

  u16* wv1T  = (u16*)alloc((size_t)2048 * 1024 * 2);   // [w1T ; v1T]
  u16* w2T   = (u16*)alloc((size_t)1024 * 1024 * 2);
  u16* wcatT = (u16*)alloc((size_t)1152 * 1024 * 2);
  u16* ff1T  = (u16*)alloc((size_t)3072 * 1024 * 2);
  u16* ff2T  = (u16*)alloc((size_t)1024 * 3072 * 2);
  u16* xm    = (u16*)alloc((size_t)NTOK * DM * 2);
  u16* x1b   = (u16*)alloc((size_t)NTOK * DM * 2);
  u16* vb    = (u16*)alloc((size_t)NTOK * DM * 2);
  u16* xcb   = (u16*)alloc((size_t)NTOK * DM * 2);
  float* dtbc = (float*)alloc((size_t)NTOK * 1152 * 4);
  float* x2  = (float*)alloc((size_t)NTOK * DM * 4);
  float* hloc = (float*)alloc((size_t)4 * NCH * 1024 * 16 * 4);  // 8 MB
  float* hin  = (float*)alloc((size_t)4 * NCH * 1024 * 16 * 4);  // 8 MB
  float* sdtb = (float*)alloc((size_t)4 * NCH * 1024 * 4);       // 512 KB
  u16* yvb  = xm;          // reuse: xm dead after fused GEMM
  u16* xn2  = x1b;         // reuse: x1 dead after conv (ln writes AFTER scan_fix reads ylb)
  u16* ylb  = x1b;         // reuse: x1 dead after conv; ylb dead before xn2 written
  u16* cdb  = (u16*)x2;    // reuse: x2 written only after scan_fix consumed cdb
  u16* hb   = xcb;         // reuse: xc+dtbc dead after scan

  const dim3 tb32(32, 8);
  // weight prep
  wtrans4<<<dim3(32, 32, 4), tb32, 0, stream>>>(w1_w, v1_w, w2_w, dt_w,
                                                wv1T, wv1T + (size_t)1024 * 1024,
                                                w2T, wcatT);
  small_trans<<<64, 256, 0, stream>>>(Bp_w, Cp_w, wcatT);
  wtrans<<<dim3(96, 32), tb32, 0, stream>>>(ff1_w, ff1T, 1024, 3072, 0, 1024);
  wtrans<<<dim3(32, 96), tb32, 0, stream>>>(ff2_w, ff2T, 3072, 1024, 0, 3072);

  // LN1 -> LN2 -> xm (bf16)
  ln_ln_kernel<<<NTOK, 256, 0, stream>>>(x, ln1_g, ln1_b, ln_g, ln_b, xm);

  // fused: x1 = xm @ w1 + b ; v = silu(xm @ v1 + b)   (N=2048)
  gemm_bt<5, 128><<<1024, 256, 0, stream>>>(xm, wv1T, w1_b, v1_b, nullptr, nullptr,
                                            x1b, vb, 1024, 1024, 16);

  // xc = silu(depthwise_conv(x1))
  conv_silu_kernel<<<(NTOK * DM) / (256 * 8), 256, 0, stream>>>(x1b, conv_w, xcb);

  // dtBC = [softplus(xc@dt_w+dt_b) | xc@Bp_w+Bp_b | xc@Cp_w+Cp_b | pad]  (f32, ld 1152)
  gemm_bt<4, 64><<<1152, 256, 0, stream>>>(xcb, wcatT, dt_b, Bp_b, Cp_b, nullptr,
                                           dtbc, nullptr, 1024, 1152, 18);

  // chunked selective scan: local scan (+ y_local, cumdt) -> combine -> parallel fix
  scan_pass1<<<2048, 256, 0, stream>>>(xcb, dtbc, A_log, D_p, hloc, sdtb, ylb, cdb);
  scan_pass2<<<256, 256, 0, stream>>>(A_log, sdtb, hloc, hin);
  scan_fix<<<2048, 256, 0, stream>>>(dtbc, ylb, cdb, vb, A_log, hin, yvb);

  // x2 = yv @ w2 + b + x (f32)
  gemm_bt<3, 64><<<1024, 256, 0, stream>>>(yvb, w2T, w2_b, nullptr, nullptr, x,
                                           x2, nullptr, 1024, 1024, 16);

  // xn2 = LN(x2) (bf16)
  ln_kernel<<<NTOK, 256, 0, stream>>>(x2, ln2_g, ln2_b, xn2);

  // h = gelu(xn2 @ ff1 + b) (bf16, ld 3072)
  gemm_bt<2, 128><<<1536, 256, 0, stream>>>(xn2, ff1T, ff1_b, nullptr, nullptr, nullptr,
                                            hb, nullptr, 1024, 3072, 24);

  // out = h @ ff2 + b + x2 (f32)
  gemm_bt<3, 64><<<1024, 256, 0, stream>>>(hb, ff2T, ff2_b, nullptr, nullptr, x2,
                                           d_out, nullptr, 3072, 1024, 16);
}

// Round 9
// 419.650 us; speedup vs baseline: 1.3670x; 1.0456x over previous
//
#include <hip/hip_runtime.h>

typedef unsigned short u16;
typedef __attribute__((ext_vector_type(8))) short short8;
typedef __attribute__((ext_vector_type(4))) float f32x4;
typedef __attribute__((ext_vector_type(4))) unsigned short u16x4;

#define SEQ 2048
#define DM 1024
#define NTOK 8192  // B*L
#define CH 64      // scan chunk length
#define NCH 32     // SEQ / CH

__device__ __forceinline__ float b2f(u16 u) {
  union { float f; unsigned int i; } x; x.i = ((unsigned int)u) << 16; return x.f;
}
__device__ __forceinline__ u16 f2b(float f) {
  union { float f; unsigned int i; } x; x.f = f;
  unsigned int i = x.i;
  unsigned int r = (i + 0x7FFFu + ((i >> 16) & 1u)) >> 16;
  return (u16)r;
}

__device__ __forceinline__ void gload16(const u16* g, u16* l) {
  __builtin_amdgcn_global_load_lds(
      (const __attribute__((address_space(1))) void*)g,
      (__attribute__((address_space(3))) void*)l, 16, 0, 0);
}

// fast gelu (exact erf via Abramowitz-Stegun 7.1.26, |err| < 1.5e-7)
__device__ __forceinline__ float gelu_f(float v) {
  const float z = fabsf(v) * 0.70710678118f;
  const float t = __builtin_amdgcn_rcpf(1.f + 0.3275911f * z);
  float poly = ((((1.061405429f * t - 1.453152027f) * t + 1.421413741f) * t
                 - 0.284496736f) * t + 0.254829592f) * t;
  float e = 1.f - poly * __expf(-z * z);
  float erfv = (v < 0.f) ? -e : e;
  return 0.5f * v * (1.f + erfv);
}
__device__ __forceinline__ float silu_f(float v) {
  return v * __builtin_amdgcn_rcpf(1.f + __expf(-v));
}
__device__ __forceinline__ float softplus_f(float v) {
  return fmaxf(v, 0.f) + __logf(1.f + __expf(-fabsf(v)));
}

// ---------------- weight transpose f32 (K x N) -> bf16 (N x K) ----------------
__global__ __launch_bounds__(256)
void wtrans(const float* __restrict__ in, u16* __restrict__ out,
            int K, int N, int rowOff, int ldOut)
{
  __shared__ float tile[32][33];
  const int n0 = blockIdx.x * 32;
  const int k0 = blockIdx.y * 32;
  const int tx = threadIdx.x, ty = threadIdx.y;
#pragma unroll
  for (int i = 0; i < 32; i += 8) {
    int k = k0 + ty + i, n = n0 + tx;
    tile[ty + i][tx] = (k < K && n < N) ? in[(long)k * N + n] : 0.f;
  }
  __syncthreads();
#pragma unroll
  for (int i = 0; i < 32; i += 8) {
    int n = n0 + ty + i, k = k0 + tx;
    if (n < N && k < K) out[(long)(rowOff + n) * ldOut + k] = f2b(tile[tx][ty + i]);
  }
}

// four 1024x1024 transposes in one launch (z-indexed)
__global__ __launch_bounds__(256)
void wtrans4(const float* __restrict__ s0, const float* __restrict__ s1,
             const float* __restrict__ s2, const float* __restrict__ s3,
             u16* __restrict__ d0, u16* __restrict__ d1,
             u16* __restrict__ d2, u16* __restrict__ d3)
{
  __shared__ float tile[32][33];
  const float* in; u16* out;
  switch (blockIdx.z) {
    case 0: in = s0; out = d0; break;
    case 1: in = s1; out = d1; break;
    case 2: in = s2; out = d2; break;
    default: in = s3; out = d3; break;
  }
  const int n0 = blockIdx.x * 32;
  const int k0 = blockIdx.y * 32;
  const int tx = threadIdx.x, ty = threadIdx.y;
#pragma unroll
  for (int i = 0; i < 32; i += 8)
    tile[ty + i][tx] = in[(long)(k0 + ty + i) * 1024 + n0 + tx];
  __syncthreads();
#pragma unroll
  for (int i = 0; i < 32; i += 8)
    out[(long)(n0 + ty + i) * 1024 + k0 + tx] = f2b(tile[tx][ty + i]);
}

// Bp_w/Cp_w (1024x16) -> rows [1024..1055] of WcatT (ld 1024); zero rows 1056..1151
__global__ __launch_bounds__(256)
void small_trans(const float* __restrict__ Bp, const float* __restrict__ Cp,
                 u16* __restrict__ wcatT)
{
  int t = blockIdx.x * 256 + threadIdx.x;  // 16384 threads
  int n = t >> 10, k = t & 1023;
  wcatT[(long)(1024 + n) * 1024 + k] = f2b(Bp[(long)k * 16 + n]);
  wcatT[(long)(1040 + n) * 1024 + k] = f2b(Cp[(long)k * 16 + n]);
#pragma unroll
  for (int i = 0; i < 6; ++i)
    wcatT[(long)1056 * 1024 + i * 16384 + t] = 0;
}

// ---------------- LayerNorm helpers ----------------
__device__ __forceinline__ void blockReduce2(float& a, float& b, float* s)
{
#pragma unroll
  for (int off = 32; off > 0; off >>= 1) {
    a += __shfl_xor(a, off);
    b += __shfl_xor(b, off);
  }
  const int lane = threadIdx.x & 63, wid = threadIdx.x >> 6;
  __syncthreads();
  if (lane == 0) { s[wid] = a; s[4 + wid] = b; }
  __syncthreads();
  a = s[0] + s[1] + s[2] + s[3];
  b = s[4] + s[5] + s[6] + s[7];
}

// fused LN1 -> LN2, f32 in, bf16 out (row length 1024, 256 thr x 4 elems)
__global__ __launch_bounds__(256)
void ln_ln_kernel(const float* __restrict__ x, const float* __restrict__ g1,
                  const float* __restrict__ b1, const float* __restrict__ g2,
                  const float* __restrict__ b2, u16* __restrict__ out)
{
  __shared__ float sred[8];
  const long row = blockIdx.x;
  const int t = threadIdx.x;
  const float4 xv = ((const float4*)(x + row * DM))[t];
  float s = xv.x + xv.y + xv.z + xv.w;
  float sq = xv.x * xv.x + xv.y * xv.y + xv.z * xv.z + xv.w * xv.w;
  blockReduce2(s, sq, sred);
  const float mu = s * (1.f / DM);
  const float rs = rsqrtf(sq * (1.f / DM) - mu * mu + 1e-5f);
  const float4 g1v = ((const float4*)g1)[t];
  const float4 b1v = ((const float4*)b1)[t];
  float xn[4];
  xn[0] = (xv.x - mu) * rs * g1v.x + b1v.x;
  xn[1] = (xv.y - mu) * rs * g1v.y + b1v.y;
  xn[2] = (xv.z - mu) * rs * g1v.z + b1v.z;
  xn[3] = (xv.w - mu) * rs * g1v.w + b1v.w;
  float s2 = xn[0] + xn[1] + xn[2] + xn[3];
  float sq2 = xn[0] * xn[0] + xn[1] * xn[1] + xn[2] * xn[2] + xn[3] * xn[3];
  blockReduce2(s2, sq2, sred);
  const float mu2 = s2 * (1.f / DM);
  const float rs2 = rsqrtf(sq2 * (1.f / DM) - mu2 * mu2 + 1e-5f);
  const float4 g2v = ((const float4*)g2)[t];
  const float4 b2v = ((const float4*)b2)[t];
  u16x4 o;
  o[0] = f2b((xn[0] - mu2) * rs2 * g2v.x + b2v.x);
  o[1] = f2b((xn[1] - mu2) * rs2 * g2v.y + b2v.y);
  o[2] = f2b((xn[2] - mu2) * rs2 * g2v.z + b2v.z);
  o[3] = f2b((xn[3] - mu2) * rs2 * g2v.w + b2v.w);
  *(u16x4*)(out + row * DM + t * 4) = o;
}

// single LN, bf16 in, bf16 out
__global__ __launch_bounds__(256)
void ln_bf_kernel(const u16* __restrict__ x, const float* __restrict__ g,
                  const float* __restrict__ b, u16* __restrict__ out)
{
  __shared__ float sred[8];
  const long row = blockIdx.x;
  const int t = threadIdx.x;
  const u16x4 xv4 = ((const u16x4*)(x + row * DM))[t];
  float xv[4];
#pragma unroll
  for (int j = 0; j < 4; ++j) xv[j] = b2f(xv4[j]);
  float s = xv[0] + xv[1] + xv[2] + xv[3];
  float sq = xv[0] * xv[0] + xv[1] * xv[1] + xv[2] * xv[2] + xv[3] * xv[3];
  blockReduce2(s, sq, sred);
  const float mu = s * (1.f / DM);
  const float rs = rsqrtf(sq * (1.f / DM) - mu * mu + 1e-5f);
  const float4 gv = ((const float4*)g)[t];
  const float4 bv = ((const float4*)b)[t];
  u16x4 o;
  o[0] = f2b((xv[0] - mu) * rs * gv.x + bv.x);
  o[1] = f2b((xv[1] - mu) * rs * gv.y + bv.y);
  o[2] = f2b((xv[2] - mu) * rs * gv.z + bv.z);
  o[3] = f2b((xv[3] - mu) * rs * gv.w + bv.w);
  *(u16x4*)(out + row * DM + t * 4) = o;
}

// ---------------- depthwise conv (k=3, pad 1 along L) + silu, vectorized ----------------
__global__ __launch_bounds__(256)
void conv_silu_kernel(const u16* __restrict__ x1, const float* __restrict__ w,
                      u16* __restrict__ xc)
{
  const long i8 = (long)blockIdx.x * 256 + threadIdx.x;  // NTOK*DM/8
  const long base = i8 * 8;
  const int d0 = (int)(base & (DM - 1));
  const long m = base >> 10;
  const int l = (int)(m & (SEQ - 1));
  const short8 cv = *(const short8*)(x1 + base);
  short8 lv = {}, rv = {};
  if (l > 0) lv = *(const short8*)(x1 + base - DM);
  if (l < SEQ - 1) rv = *(const short8*)(x1 + base + DM);
  short8 o;
#pragma unroll
  for (int j = 0; j < 8; ++j) {
    const int d = d0 + j;
    const float a = b2f((u16)lv[j]) * w[d * 3 + 0] + b2f((u16)cv[j]) * w[d * 3 + 1]
                  + b2f((u16)rv[j]) * w[d * 3 + 2];
    o[j] = (short)f2b(silu_f(a));
  }
  *(short8*)(xc + base) = o;
}

// ---------------- GEMM: 128xBN tile, NU K-subtiles per barrier ------------------
// MODE 2: bf16 out = gelu(acc + bias)
// MODE 4: dtBC: col<1024 -> bf16 softplus to outp (ld 1024); cols 1024..1055 -> f32
//         to outp2 (ld 32, +bias2/+bias3); col>=1056 skipped
// MODE 5: fused w1|v1 (N=2048): col<1024 -> outp (bf16, +bias); else silu -> outp2
// MODE 6: bf16 out = acc + bias + resid(f32)
// MODE 7: f32  out = acc + bias + resid(bf16)
template <int MODE, int BN, int NU>
__global__ __launch_bounds__(256)
void gemm_bt(const u16* __restrict__ A, const u16* __restrict__ BT,
             const float* __restrict__ bias, const float* __restrict__ bias2,
             const float* __restrict__ bias3, const float* __restrict__ resid,
             void* __restrict__ outp, void* __restrict__ outp2,
             int K, int ldOut, int nbx)
{
  constexpr int NF = BN / 32;            // B col fragments per wave: 4 or 2
  constexpr int ASZ = 4096 * NU;         // u16 per A buffer
  constexpr int BSUB = BN * 32;          // u16 per B subtile
  constexpr int BSZ = BSUB * NU;
  __shared__ u16 lds_a[2][ASZ];
  __shared__ u16 lds_b[2][BSZ];
  const int t = threadIdx.x;
  const int lane = t & 63;
  const int wid = t >> 6;
  const int wr = wid >> 1, wc = wid & 1;

  int bid = blockIdx.x;
  const int qch = gridDim.x >> 3;
  bid = (bid & 7) * qch + (bid >> 3);
  const long brow = (long)(bid / nbx) * 128;
  const long bcol = (long)(bid % nbx) * BN;

  f32x4 acc[4][NF] = {};

  const int srow = t >> 2;
  const int sslot = (t & 3) ^ ((t >> 3) & 3);
  const u16* aPtr = A + (brow + srow) * (long)K + sslot * 8;
  const u16* bPtr = BT + (bcol + srow) * (long)K + sslot * 8;
  u16* la = &lds_a[0][t * 8];
  u16* lb = &lds_b[0][t * 8];
  const long rowStep = 64L * K;
  const int nk = K / (32 * NU);

  const int rslot = (lane >> 4) ^ ((lane >> 1) & 3);
  const int koff = rslot * 8;
  const int arow = wr * 64 + (lane & 15);
  const int brw = (BN == 128 ? wc * 64 : wc * 32) + (lane & 15);

#define STAGE(kt, buf)                                                        \
  {                                                                           \
    _Pragma("unroll")                                                         \
    for (int su_ = 0; su_ < NU; ++su_) {                                      \
      const int k0_ = (((kt) * NU + su_) << 5);                               \
      gload16(aPtr + k0_, la + (buf) * ASZ + su_ * 4096);                     \
      gload16(aPtr + rowStep + k0_, la + (buf) * ASZ + su_ * 4096 + 2048);    \
      gload16(bPtr + k0_, lb + (buf) * BSZ + su_ * BSUB);                     \
      if constexpr (BN == 128)                                                \
        gload16(bPtr + rowStep + k0_, lb + (buf) * BSZ + su_ * BSUB + 2048);  \
    }                                                                         \
  }

  STAGE(0, 0);
  __syncthreads();
  int cur = 0;
  for (int kt = 0; kt < nk; ++kt) {
    if (kt + 1 < nk) STAGE(kt + 1, cur ^ 1);
#pragma unroll
    for (int su = 0; su < NU; ++su) {
      const u16* pa = &lds_a[cur][su * 4096];
      const u16* pb = &lds_b[cur][su * BSUB];
      short8 af[4], bfr[NF];
#pragma unroll
      for (int m = 0; m < 4; ++m)
        af[m] = *(const short8*)&pa[(arow + m * 16) * 32 + koff];
#pragma unroll
      for (int n = 0; n < NF; ++n)
        bfr[n] = *(const short8*)&pb[(brw + n * 16) * 32 + koff];
#pragma unroll
      for (int m = 0; m < 4; ++m)
#pragma unroll
        for (int n = 0; n < NF; ++n)
          acc[m][n] = __builtin_amdgcn_mfma_f32_16x16x32_bf16(af[m], bfr[n], acc[m][n], 0, 0, 0);
    }
    __syncthreads();
    cur ^= 1;
  }
#undef STAGE

  const int cc = lane & 15;
  const int r0 = (lane >> 4) * 4;
#pragma unroll
  for (int m = 0; m < 4; ++m) {
#pragma unroll
    for (int n = 0; n < NF; ++n) {
      const long col = bcol + (BN == 128 ? wc * 64 : wc * 32) + n * 16 + cc;
#pragma unroll
      for (int r = 0; r < 4; ++r) {
        const long row = brow + wr * 64 + m * 16 + r0 + r;
        float val = acc[m][n][r];
        if constexpr (MODE == 4) {
          if (col < 1024) {
            ((u16*)outp)[row * 1024 + col] = f2b(softplus_f(val + bias[col]));
          } else if (col < 1040) {
            ((float*)outp2)[row * 32 + col - 1024] = val + bias2[col - 1024];
          } else if (col < 1056) {
            ((float*)outp2)[row * 32 + col - 1024] = val + bias3[col - 1040];
          }
        } else if constexpr (MODE == 5) {
          if (col < 1024) {
            val += bias[col];
            ((u16*)outp)[row * 1024 + col] = f2b(val);
          } else {
            ((u16*)outp2)[row * 1024 + col - 1024] = f2b(silu_f(val + bias2[col - 1024]));
          }
        } else if constexpr (MODE == 6) {
          val += bias[col];
          ((u16*)outp)[row * ldOut + col] = f2b(val + resid[row * ldOut + col]);
        } else if constexpr (MODE == 7) {
          val += bias[col];
          ((float*)outp)[row * ldOut + col] = val + b2f(((const u16*)resid)[row * ldOut + col]);
        } else {  // MODE 2
          ((u16*)outp)[row * ldOut + col] = f2b(gelu_f(val + bias[col]));
        }
      }
    }
  }
}

// ---------------- chunked selective scan ----------------
// pass 1: local scan (h0=0): h_out/chunk + sum(dt) + y_local + inclusive cumdt (bf16)
__global__ __launch_bounds__(256)
void scan_pass1(const u16* __restrict__ xc, const u16* __restrict__ dtb,
                const float* __restrict__ bcb, const float* __restrict__ A_log,
                const float* __restrict__ D_p, float* __restrict__ hloc,
                float* __restrict__ sdt, u16* __restrict__ ylb, u16* __restrict__ cdb)
{
  const int bx = blockIdx.x;
  const int b = bx >> 9;
  const int ch = (bx >> 4) & 31;
  const int dBase = (bx & 15) * 64;
  const int t = threadIdx.x;
  const int dl = t >> 2;
  const int q = t & 3;
  const int d = dBase + dl;

  __shared__ float s_bc[32][32];
  __shared__ u16 s_dt[32][64];
  __shared__ u16 s_x[32][64];
  __shared__ u16 s_yl[32][64];
  __shared__ u16 s_cd[32][64];

  float Areg[4];
#pragma unroll
  for (int j = 0; j < 4; ++j) Areg[j] = -__expf(A_log[d * 16 + q * 4 + j]);
  const float Dp = D_p[d];
  float h[4] = {0.f, 0.f, 0.f, 0.f};
  float sAcc = 0.f;
  const long mBase = (long)b * SEQ + ch * CH;

  for (int c0 = 0; c0 < CH; c0 += 32) {
#pragma unroll
    for (int i = 0; i < 4; ++i) {
      int idx = i * 256 + t;
      int s = idx >> 5, j = idx & 31;
      s_bc[s][j] = bcb[(mBase + c0 + s) * 32 + j];
    }
#pragma unroll
    for (int i = 0; i < 8; ++i) {
      int idx = i * 256 + t;
      int s = idx >> 6, j = idx & 63;
      long m = mBase + c0 + s;
      s_dt[s][j] = dtb[m * DM + dBase + j];
      s_x[s][j] = xc[m * DM + dBase + j];
    }
    __syncthreads();
#pragma unroll 4
    for (int s = 0; s < 32; ++s) {
      const float dt = b2f(s_dt[s][dl]);
      const float xt = b2f(s_x[s][dl]);
      const float p = dt * xt;
      sAcc += dt;
      float y = 0.f;
#pragma unroll
      for (int j = 0; j < 4; ++j) {
        h[j] = __expf(dt * Areg[j]) * h[j] + p * s_bc[s][q * 4 + j];
        y = fmaf(h[j], s_bc[s][16 + q * 4 + j], y);
      }
      y += __shfl_xor(y, 1);
      y += __shfl_xor(y, 2);
      if (q == 0) s_yl[s][dl] = f2b(y + Dp * xt);
      if (q == 1) s_cd[s][dl] = f2b(sAcc);
    }
    __syncthreads();
#pragma unroll
    for (int i = 0; i < 8; ++i) {
      int idx = i * 256 + t;
      int s = idx >> 6, j = idx & 63;
      long m = mBase + c0 + s;
      ylb[m * DM + dBase + j] = s_yl[s][j];
      cdb[m * DM + dBase + j] = s_cd[s][j];
    }
    __syncthreads();
  }
  const long base = (((long)b * NCH + ch) * 1024 + d) * 16 + q * 4;
  float4 hv; hv.x = h[0]; hv.y = h[1]; hv.z = h[2]; hv.w = h[3];
  *(float4*)&hloc[base] = hv;
  if (q == 0) sdt[((long)b * NCH + ch) * 1024 + d] = sAcc;
}

// pass 2: sequential combine over chunks
__global__ __launch_bounds__(256)
void scan_pass2(const float* __restrict__ A_log, const float* __restrict__ sdt,
                const float* __restrict__ hloc, float* __restrict__ hin)
{
  const int tid = blockIdx.x * 256 + threadIdx.x;
  const int b = tid >> 14;
  const int dn = tid & 16383;
  const int d = dn >> 4;
  const float A = -__expf(A_log[dn]);
  float h = 0.f;
  for (int c = 0; c < NCH; ++c) {
    const long idx = (((long)b * NCH + c) << 14) + dn;
    hin[idx] = h;
    h = __expf(A * sdt[((long)b * NCH + c) * 1024 + d]) * h + hloc[idx];
  }
}

// pass 3 (parallel): yv = (y_local + sum_n C[t,n]*hin[n]*exp(A_n*cumdt)) * v
__global__ __launch_bounds__(256)
void scan_fix(const float* __restrict__ bcb, const u16* __restrict__ ylb,
              const u16* __restrict__ cdb, const u16* __restrict__ vg,
              const float* __restrict__ A_log, const float* __restrict__ hin,
              u16* __restrict__ yv)
{
  const int bx = blockIdx.x;
  const int b = bx >> 9;
  const int ch = (bx >> 4) & 31;
  const int dBase = (bx & 15) * 64;
  const int t = threadIdx.x;
  const int dl = t >> 2;
  const int q = t & 3;
  const int d = dBase + dl;

  __shared__ float s_c[32][16];
  __shared__ u16 s_cd[32][64];
  __shared__ u16 s_yl[32][64];
  __shared__ u16 s_v[32][64];
  __shared__ u16 s_o[32][64];

  float Areg[4];
#pragma unroll
  for (int j = 0; j < 4; ++j) Areg[j] = -__expf(A_log[d * 16 + q * 4 + j]);
  const float4 hv4 = *(const float4*)&hin[(((long)b * NCH + ch) * 1024 + d) * 16 + q * 4];
  const float hv[4] = {hv4.x, hv4.y, hv4.z, hv4.w};

  const long mBase = (long)b * SEQ + ch * CH;

  for (int c0 = 0; c0 < CH; c0 += 32) {
#pragma unroll
    for (int i = 0; i < 2; ++i) {
      int idx = i * 256 + t;
      int s = idx >> 4, j = idx & 15;
      s_c[s][j] = bcb[(mBase + c0 + s) * 32 + 16 + j];
    }
#pragma unroll
    for (int i = 0; i < 8; ++i) {
      int idx = i * 256 + t;
      int s = idx >> 6, j = idx & 63;
      long m = mBase + c0 + s;
      s_cd[s][j] = cdb[m * DM + dBase + j];
      s_yl[s][j] = ylb[m * DM + dBase + j];
      s_v[s][j] = vg[m * DM + dBase + j];
    }
    __syncthreads();
#pragma unroll 4
    for (int s = 0; s < 32; ++s) {
      const float cd = b2f(s_cd[s][dl]);
      float corr = 0.f;
#pragma unroll
      for (int j = 0; j < 4; ++j)
        corr = fmaf(s_c[s][q * 4 + j] * hv[j], __expf(Areg[j] * cd), corr);
      corr += __shfl_xor(corr, 1);
      corr += __shfl_xor(corr, 2);
      if (q == 0)
        s_o[s][dl] = f2b((b2f(s_yl[s][dl]) + corr) * b2f(s_v[s][dl]));
    }
    __syncthreads();
#pragma unroll
    for (int i = 0; i < 8; ++i) {
      int idx = i * 256 + t;
      int s = idx >> 6, j = idx & 63;
      yv[(mBase + c0 + s) * DM + dBase + j] = s_o[s][j];
    }
    __syncthreads();
  }
}

extern "C" void kernel_launch(void* const* d_in, const int* in_sizes, int n_in,
                              void* d_out, int out_size, void* d_ws, size_t ws_size,
                              hipStream_t stream)
{
  (void)in_sizes; (void)n_in; (void)out_size; (void)ws_size;
  const float* x      = (const float*)d_in[0];
  const float* ln1_g  = (const float*)d_in[1];
  const float* ln1_b  = (const float*)d_in[2];
  const float* ln_g   = (const float*)d_in[3];
  const float* ln_b   = (const float*)d_in[4];
  const float* w1_w   = (const float*)d_in[5];
  const float* w1_b   = (const float*)d_in[6];
  const float* v1_w   = (const float*)d_in[7];
  const float* v1_b   = (const float*)d_in[8];
  const float* w2_w   = (const float*)d_in[9];
  const float* w2_b   = (const float*)d_in[10];
  const float* conv_w = (const float*)d_in[11];
  const float* dt_w   = (const float*)d_in[12];
  const float* dt_b   = (const float*)d_in[13];
  const float* Bp_w   = (const float*)d_in[14];
  const float* Bp_b   = (const float*)d_in[15];
  const float* Cp_w   = (const float*)d_in[16];
  const float* Cp_b   = (const float*)d_in[17];
  const float* A_log  = (const float*)d_in[18];
  const float* D_p    = (const float*)d_in[19];
  const float* ln2_g  = (const float*)d_in[20];
  const float* ln2_b  = (const float*)d_in[21];
  const float* ff1_w  = (const float*)d_in[22];
  const float* ff1_b  = (const float*)d_in[23];
  const float* ff2_w  = (const float*)d_in[24];
  const float* ff2_b  = (const float*)d_in[25];

  char* ws = (char*)d_ws;
  size_t cur = 0;
  auto alloc = [&](size_t bytes) -> void* {
    void* p = ws + cur;
    cur = (cur + bytes + 255) & ~(size_t)255;
    return p;
  };

  u16* wv1T  = (u16*)alloc((size_t)2048 * 1024 * 2);   // [w1T ; v1T]
  u16* w2T   = (u16*)alloc((size_t)1024 * 1024 * 2);
  u16* wcatT = (u16*)alloc((size_t)1152 * 1024 * 2);
  u16* ff1T  = (u16*)alloc((size_t)3072 * 1024 * 2);
  u16* ff2T  = (u16*)alloc((size_t)1024 * 3072 * 2);
  u16* xm    = (u16*)alloc((size_t)NTOK * DM * 2);
  u16* x1b   = (u16*)alloc((size_t)NTOK * DM * 2);
  u16* vb    = (u16*)alloc((size_t)NTOK * DM * 2);     // 16 MB
  u16* xcb   = (u16*)alloc((size_t)NTOK * DM * 2);     // 16 MB (contiguous after vb)
  u16* dtb   = (u16*)alloc((size_t)NTOK * DM * 2);     // 16 MB (contiguous after xcb)
  float* bcb = (float*)alloc((size_t)NTOK * 32 * 4);   // [B|C] compact f32
  u16* x2u   = (u16*)alloc((size_t)NTOK * DM * 2);     // x2 bf16
  float* hloc = (float*)alloc((size_t)4 * NCH * 1024 * 16 * 4);  // 8 MB
  float* hin  = (float*)alloc((size_t)4 * NCH * 1024 * 16 * 4);  // 8 MB
  float* sdtb = (float*)alloc((size_t)4 * NCH * 1024 * 4);       // 512 KB
  u16* yvb  = xm;          // reuse: xm dead after fused GEMM; consumed by w2
  u16* ylb  = x1b;         // reuse: x1 dead after conv; consumed by scan_fix
  u16* xn2  = x1b;         // reuse: ylb dead before LN writes xn2
  u16* cdb  = x2u;         // reuse: consumed by scan_fix before w2 writes x2u
  u16* hb   = vb;          // reuse: vb+xcb+dtb = exactly 48 MB contiguous, all dead
                           // after scan_fix; ff1 output (8192x3072 bf16 = 48 MB)

  const dim3 tb32(32, 8);
  // weight prep
  wtrans4<<<dim3(32, 32, 4), tb32, 0, stream>>>(w1_w, v1_w, w2_w, dt_w,
                                                wv1T, wv1T + (size_t)1024 * 1024,
                                                w2T, wcatT);
  small_trans<<<64, 256, 0, stream>>>(Bp_w, Cp_w, wcatT);
  wtrans<<<dim3(96, 32), tb32, 0, stream>>>(ff1_w, ff1T, 1024, 3072, 0, 1024);
  wtrans<<<dim3(32, 96), tb32, 0, stream>>>(ff2_w, ff2T, 3072, 1024, 0, 3072);

  // LN1 -> LN2 -> xm (bf16)
  ln_ln_kernel<<<NTOK, 256, 0, stream>>>(x, ln1_g, ln1_b, ln_g, ln_b, xm);

  // fused: x1 = xm @ w1 + b ; v = silu(xm @ v1 + b)   (N=2048)
  gemm_bt<5, 128, 1><<<1024, 256, 0, stream>>>(xm, wv1T, w1_b, v1_b, nullptr, nullptr,
                                               x1b, vb, 1024, 1024, 16);

  // xc = silu(depthwise_conv(x1))
  conv_silu_kernel<<<(NTOK * DM) / (256 * 8), 256, 0, stream>>>(x1b, conv_w, xcb);

  // dt (bf16, softplus) + BC (compact f32): N=1088 grid (cols>=1088 all-pad skipped)
  gemm_bt<4, 64, 1><<<1088, 256, 0, stream>>>(xcb, wcatT, dt_b, Bp_b, Cp_b, nullptr,
                                              dtb, bcb, 1024, 1024, 17);

  // chunked selective scan: local scan (+ y_local, cumdt) -> combine -> parallel fix
  scan_pass1<<<2048, 256, 0, stream>>>(xcb, dtb, bcb, A_log, D_p, hloc, sdtb, ylb, cdb);
  scan_pass2<<<256, 256, 0, stream>>>(A_log, sdtb, hloc, hin);
  scan_fix<<<2048, 256, 0, stream>>>(bcb, ylb, cdb, vb, A_log, hin, yvb);

  // x2 = yv @ w2 + b + x  (bf16 out, f32 resid)
  gemm_bt<6, 64, 1><<<1024, 256, 0, stream>>>(yvb, w2T, w2_b, nullptr, nullptr, x,
                                              x2u, nullptr, 1024, 1024, 16);

  // xn2 = LN(x2) (bf16 in/out)
  ln_bf_kernel<<<NTOK, 256, 0, stream>>>(x2u, ln2_g, ln2_b, xn2);

  // h = gelu(xn2 @ ff1 + b) (bf16, ld 3072)
  gemm_bt<2, 128, 1><<<1536, 256, 0, stream>>>(xn2, ff1T, ff1_b, nullptr, nullptr, nullptr,
                                               hb, nullptr, 1024, 3072, 24);

  // out = h @ ff2 + b + x2  (f32 out, bf16 resid; BK=64 pipeline)
  gemm_bt<7, 128, 2><<<512, 256, 0, stream>>>(hb, ff2T, ff2_b, nullptr, nullptr,
                                              (const float*)x2u, d_out, nullptr,
                                              3072, 1024, 8);
}